// Round 1
// baseline (1830.077 us; speedup 1.0000x reference)
//
#include <hip/hip_runtime.h>

#define NN 50000
#define NE 800000
#define NG 64
#define FIN0 128
#define HID 128
#define DOUT 64
#define LN_EPS 1e-5f
#define SCAN_T 512

// ---------------- CSR build ----------------
__global__ __launch_bounds__(256) void k_zero_int(int* p, int n) {
  int i = blockIdx.x * 256 + threadIdx.x;
  if (i < n) p[i] = 0;
}

__global__ __launch_bounds__(256) void k_deg(const int* __restrict__ dst,
                                             int* __restrict__ deg, int e) {
  int i = blockIdx.x * 256 + threadIdx.x;
  if (i < e) atomicAdd(&deg[dst[i]], 1);
}

__global__ __launch_bounds__(SCAN_T) void k_scan_a(const int* __restrict__ deg,
                                                   int* __restrict__ rowptr,
                                                   int* __restrict__ blocksum, int n) {
  __shared__ int s[SCAN_T];
  int t = threadIdx.x, b = blockIdx.x, i = b * SCAN_T + t;
  int v = (i < n) ? deg[i] : 0;
  s[t] = v;
  __syncthreads();
  for (int off = 1; off < SCAN_T; off <<= 1) {
    int x = (t >= off) ? s[t - off] : 0;
    __syncthreads();
    s[t] += x;
    __syncthreads();
  }
  if (i < n) rowptr[i] = s[t] - v;  // exclusive
  if (t == SCAN_T - 1) blocksum[b] = s[t];
}

__global__ __launch_bounds__(128) void k_scan_b(int* __restrict__ blocksum, int nb) {
  __shared__ int s[128];
  int t = threadIdx.x;
  int v = (t < nb) ? blocksum[t] : 0;
  s[t] = v;
  __syncthreads();
  for (int off = 1; off < 128; off <<= 1) {
    int x = (t >= off) ? s[t - off] : 0;
    __syncthreads();
    s[t] += x;
    __syncthreads();
  }
  if (t < nb) blocksum[t] = s[t] - v;  // exclusive
}

__global__ __launch_bounds__(SCAN_T) void k_scan_c(const int* __restrict__ deg,
                                                   int* __restrict__ rowptr,
                                                   const int* __restrict__ blocksum,
                                                   int* __restrict__ cursor,
                                                   float* __restrict__ dis,
                                                   float* __restrict__ invc, int n, int e) {
  int t = threadIdx.x, b = blockIdx.x;
  int i = b * SCAN_T + t;
  if (i < n) {
    int r = rowptr[i] + blocksum[b];
    rowptr[i] = r;
    cursor[i] = r;
    int d = deg[i];
    dis[i] = rsqrtf((float)(d + 1));
    invc[i] = (d > 0) ? 1.0f / (float)d : 1.0f;
  }
  if (i == 0) rowptr[n] = e;
}

__global__ __launch_bounds__(256) void k_fill(const int* __restrict__ src,
                                              const int* __restrict__ dst,
                                              const float* __restrict__ ea,
                                              int* __restrict__ cursor,
                                              int* __restrict__ csrc,
                                              float* __restrict__ cea, int e) {
  int i = blockIdx.x * 256 + threadIdx.x;
  if (i < e) {
    int d = dst[i];
    int pos = atomicAdd(&cursor[d], 1);
    csrc[pos] = src[i];
    cea[pos] = ea[i];
  }
}

// ---------------- GEMM: Y[n,FOUT] = X[n,128] @ W[128,FOUT] ----------------
template <int FOUT>
__global__ __launch_bounds__(256) void k_gemm(const float* __restrict__ X,
                                              const float* __restrict__ W,
                                              float* __restrict__ Y, int n) {
  const int FI = 128;
  __shared__ __align__(16) float xs[32][FI];
  int t = threadIdx.x;
  int row0 = blockIdx.x * 32;
  for (int i = t; i < 32 * FI / 4; i += 256) {
    int r = i / (FI / 4);
    int c = i % (FI / 4);
    float4 v = make_float4(0.f, 0.f, 0.f, 0.f);
    if (row0 + r < n) v = ((const float4*)(X + (size_t)(row0 + r) * FI))[c];
    ((float4*)xs[r])[c] = v;
  }
  __syncthreads();
  const int CG = FOUT / 2;     // threads covering column-pairs
  const int RG = 256 / CG;     // row groups (4 for 128, 8 for 64)
  const int RPT = 32 / RG;     // rows per thread (8 or 4)
  int jp = t % CG;             // column pair index
  int rg = t / CG;
  float accx[RPT], accy[RPT];
#pragma unroll
  for (int r = 0; r < RPT; r++) { accx[r] = 0.f; accy[r] = 0.f; }
  for (int k4 = 0; k4 < FI / 4; k4++) {
    float4 xv[RPT];
#pragma unroll
    for (int r = 0; r < RPT; r++) xv[r] = ((const float4*)xs[rg * RPT + r])[k4];
#pragma unroll
    for (int kk = 0; kk < 4; kk++) {
      float2 w = ((const float2*)(W + (size_t)(4 * k4 + kk) * FOUT))[jp];
      float xk;
#pragma unroll
      for (int r = 0; r < RPT; r++) {
        xk = (kk == 0) ? xv[r].x : (kk == 1) ? xv[r].y : (kk == 2) ? xv[r].z : xv[r].w;
        accx[r] += xk * w.x;
        accy[r] += xk * w.y;
      }
    }
  }
#pragma unroll
  for (int r = 0; r < RPT; r++) {
    int row = row0 + rg * RPT + r;
    if (row < n) {
      float2 o = {accx[r], accy[r]};
      ((float2*)(Y + (size_t)row * FOUT))[jp] = o;
    }
  }
}

// ---------------- GCN aggregation: H = agg + dis^2*XW + bias ----------------
template <int F>
__global__ __launch_bounds__(256) void k_agg(const float* __restrict__ XW,
                                             const float* __restrict__ dis,
                                             const int* __restrict__ rowptr,
                                             const int* __restrict__ csrc,
                                             const float* __restrict__ bias,
                                             float* __restrict__ H, int n) {
  int lane = threadIdx.x & 63;
  int node = blockIdx.x * 4 + (threadIdx.x >> 6);
  if (node >= n) return;
  float dn = dis[node];
  int beg = rowptr[node], end = rowptr[node + 1];
  if (F == 128) {
    const float2* xw2 = (const float2*)XW;
    float2 acc = {0.f, 0.f};
    int i = beg;
    for (; i + 4 <= end; i += 4) {
      int s0 = csrc[i], s1 = csrc[i + 1], s2 = csrc[i + 2], s3 = csrc[i + 3];
      float n0 = dn * dis[s0], n1 = dn * dis[s1], n2 = dn * dis[s2], n3 = dn * dis[s3];
      float2 v0 = xw2[(size_t)s0 * 64 + lane];
      float2 v1 = xw2[(size_t)s1 * 64 + lane];
      float2 v2 = xw2[(size_t)s2 * 64 + lane];
      float2 v3 = xw2[(size_t)s3 * 64 + lane];
      acc.x += n0 * v0.x + n1 * v1.x + n2 * v2.x + n3 * v3.x;
      acc.y += n0 * v0.y + n1 * v1.y + n2 * v2.y + n3 * v3.y;
    }
    for (; i < end; i++) {
      int s = csrc[i];
      float nr = dn * dis[s];
      float2 v = xw2[(size_t)s * 64 + lane];
      acc.x += nr * v.x;
      acc.y += nr * v.y;
    }
    float2 self = xw2[(size_t)node * 64 + lane];
    float2 bb = ((const float2*)bias)[lane];
    float d2 = dn * dn;
    float2 h = {acc.x + d2 * self.x + bb.x, acc.y + d2 * self.y + bb.y};
    ((float2*)H)[(size_t)node * 64 + lane] = h;
  } else {
    float acc = 0.f;
    int i = beg;
    for (; i + 4 <= end; i += 4) {
      int s0 = csrc[i], s1 = csrc[i + 1], s2 = csrc[i + 2], s3 = csrc[i + 3];
      float n0 = dn * dis[s0], n1 = dn * dis[s1], n2 = dn * dis[s2], n3 = dn * dis[s3];
      acc += n0 * XW[(size_t)s0 * F + lane] + n1 * XW[(size_t)s1 * F + lane] +
             n2 * XW[(size_t)s2 * F + lane] + n3 * XW[(size_t)s3 * F + lane];
    }
    for (; i < end; i++) {
      int s = csrc[i];
      acc += dn * dis[s] * XW[(size_t)s * F + lane];
    }
    float d2 = dn * dn;
    H[(size_t)node * F + lane] = acc + d2 * XW[(size_t)node * F + lane] + bias[lane];
  }
}

// ------- mean-aggregation of h[src]+relu(ea*ew+eb), optional ReLU+LN -------
template <int F, bool DO_LN>
__global__ __launch_bounds__(256) void k_msg(const float* __restrict__ H,
                                             const float* __restrict__ ew,
                                             const float* __restrict__ eb,
                                             const int* __restrict__ rowptr,
                                             const int* __restrict__ csrc,
                                             const float* __restrict__ cea,
                                             const float* __restrict__ invc,
                                             const float* __restrict__ lng,
                                             const float* __restrict__ lnb,
                                             float* __restrict__ OUT, int n) {
  int lane = threadIdx.x & 63;
  int node = blockIdx.x * 4 + (threadIdx.x >> 6);
  if (node >= n) return;
  int beg = rowptr[node], end = rowptr[node + 1];
  if (F == 128) {
    const float2* h2 = (const float2*)H;
    float2 w = ((const float2*)ew)[lane];
    float2 b = ((const float2*)eb)[lane];
    float2 acc = {0.f, 0.f};
    int i = beg;
    for (; i + 4 <= end; i += 4) {
      int s0 = csrc[i], s1 = csrc[i + 1], s2 = csrc[i + 2], s3 = csrc[i + 3];
      float a0 = cea[i], a1 = cea[i + 1], a2 = cea[i + 2], a3 = cea[i + 3];
      float2 v0 = h2[(size_t)s0 * 64 + lane];
      float2 v1 = h2[(size_t)s1 * 64 + lane];
      float2 v2 = h2[(size_t)s2 * 64 + lane];
      float2 v3 = h2[(size_t)s3 * 64 + lane];
      acc.x += v0.x + fmaxf(a0 * w.x + b.x, 0.f) + v1.x + fmaxf(a1 * w.x + b.x, 0.f) +
               v2.x + fmaxf(a2 * w.x + b.x, 0.f) + v3.x + fmaxf(a3 * w.x + b.x, 0.f);
      acc.y += v0.y + fmaxf(a0 * w.y + b.y, 0.f) + v1.y + fmaxf(a1 * w.y + b.y, 0.f) +
               v2.y + fmaxf(a2 * w.y + b.y, 0.f) + v3.y + fmaxf(a3 * w.y + b.y, 0.f);
    }
    for (; i < end; i++) {
      int s = csrc[i];
      float a = cea[i];
      float2 v = h2[(size_t)s * 64 + lane];
      acc.x += v.x + fmaxf(a * w.x + b.x, 0.f);
      acc.y += v.y + fmaxf(a * w.y + b.y, 0.f);
    }
    float ic = invc[node];
    float2 o = {acc.x * ic, acc.y * ic};
    if (DO_LN) {
      o.x = fmaxf(o.x, 0.f);
      o.y = fmaxf(o.y, 0.f);
      float s1 = o.x + o.y;
      float s2 = o.x * o.x + o.y * o.y;
      for (int off = 32; off; off >>= 1) {
        s1 += __shfl_xor(s1, off, 64);
        s2 += __shfl_xor(s2, off, 64);
      }
      float mu = s1 * (1.f / 128.f);
      float var = s2 * (1.f / 128.f) - mu * mu;
      float r = rsqrtf(var + LN_EPS);
      float2 g = ((const float2*)lng)[lane];
      float2 bb = ((const float2*)lnb)[lane];
      o.x = (o.x - mu) * r * g.x + bb.x;
      o.y = (o.y - mu) * r * g.y + bb.y;
    }
    ((float2*)OUT)[(size_t)node * 64 + lane] = o;
  } else {
    float w = ew[lane], b = eb[lane];
    float acc = 0.f;
    int i = beg;
    for (; i + 4 <= end; i += 4) {
      int s0 = csrc[i], s1 = csrc[i + 1], s2 = csrc[i + 2], s3 = csrc[i + 3];
      float a0 = cea[i], a1 = cea[i + 1], a2 = cea[i + 2], a3 = cea[i + 3];
      acc += H[(size_t)s0 * F + lane] + fmaxf(a0 * w + b, 0.f) +
             H[(size_t)s1 * F + lane] + fmaxf(a1 * w + b, 0.f) +
             H[(size_t)s2 * F + lane] + fmaxf(a2 * w + b, 0.f) +
             H[(size_t)s3 * F + lane] + fmaxf(a3 * w + b, 0.f);
    }
    for (; i < end; i++) {
      int s = csrc[i];
      acc += H[(size_t)s * F + lane] + fmaxf(cea[i] * w + b, 0.f);
    }
    OUT[(size_t)node * F + lane] = acc * invc[node];
  }
}

// ---------------- global mean pool (batch sorted) ----------------
__global__ __launch_bounds__(256) void k_pool(const float* __restrict__ H,
                                              const int* __restrict__ batch,
                                              float* __restrict__ Z, int n) {
  int g = blockIdx.x;
  __shared__ int sbeg, send;
  __shared__ float part[4][64];
  if (threadIdx.x == 0) {
    int lo = 0, hi = n;
    while (lo < hi) { int m = (lo + hi) >> 1; if (batch[m] < g) lo = m + 1; else hi = m; }
    sbeg = lo;
    lo = 0; hi = n;
    while (lo < hi) { int m = (lo + hi) >> 1; if (batch[m] < g + 1) lo = m + 1; else hi = m; }
    send = lo;
  }
  __syncthreads();
  int beg = sbeg, end = send;
  int lane = threadIdx.x & 63, wv = threadIdx.x >> 6;
  float acc = 0.f;
  for (int i = beg + wv; i < end; i += 4) acc += H[(size_t)i * 64 + lane];
  part[wv][lane] = acc;
  __syncthreads();
  if (wv == 0) {
    float s = part[0][lane] + part[1][lane] + part[2][lane] + part[3][lane];
    float c = (float)(end - beg);
    if (c < 1.f) c = 1.f;
    Z[g * 64 + lane] = s / c;
  }
}

extern "C" void kernel_launch(void* const* d_in, const int* in_sizes, int n_in,
                              void* d_out, int out_size, void* d_ws, size_t ws_size,
                              hipStream_t stream) {
  const float* x = (const float*)d_in[0];
  const int* ei = (const int*)d_in[1];
  const float* ea = (const float*)d_in[2];
  const int* batch = (const int*)d_in[3];
  const float* gw0 = (const float*)d_in[4];
  const float* gb0 = (const float*)d_in[5];
  const float* ew0 = (const float*)d_in[6];
  const float* eb0 = (const float*)d_in[7];
  const float* lg0 = (const float*)d_in[8];
  const float* lb0 = (const float*)d_in[9];
  const float* gw1 = (const float*)d_in[10];
  const float* gb1 = (const float*)d_in[11];
  const float* ew1 = (const float*)d_in[12];
  const float* eb1 = (const float*)d_in[13];
  const float* lg1 = (const float*)d_in[14];
  const float* lb1 = (const float*)d_in[15];
  const float* gw2 = (const float*)d_in[16];
  const float* gb2 = (const float*)d_in[17];
  const float* ew2 = (const float*)d_in[18];
  const float* eb2 = (const float*)d_in[19];
  float* out = (float*)d_out;

  const int* src = ei;
  const int* dst = ei + NE;

  char* w = (char*)d_ws;
  size_t off = 0;
  auto alloc = [&](size_t bytes) -> void* {
    void* p = (void*)(w + off);
    off = (off + bytes + 255) & ~(size_t)255;
    return p;
  };
  int* deg = (int*)alloc(NN * sizeof(int));
  int* rowptr = (int*)alloc((NN + 1) * sizeof(int));
  int* blocksum = (int*)alloc(128 * sizeof(int));
  int* cursor = (int*)alloc(NN * sizeof(int));
  int* csrc = (int*)alloc(NE * sizeof(int));
  float* cea = (float*)alloc(NE * sizeof(float));
  float* dis = (float*)alloc(NN * sizeof(float));
  float* invc = (float*)alloc(NN * sizeof(float));
  float* B1 = (float*)alloc((size_t)NN * 128 * sizeof(float));
  float* B2 = (float*)alloc((size_t)NN * 128 * sizeof(float));

  const int nb_scan = (NN + SCAN_T - 1) / SCAN_T;  // 98

  hipLaunchKernelGGL(k_zero_int, dim3((NN + 255) / 256), dim3(256), 0, stream, deg, NN);
  hipLaunchKernelGGL(k_deg, dim3((NE + 255) / 256), dim3(256), 0, stream, dst, deg, NE);
  hipLaunchKernelGGL(k_scan_a, dim3(nb_scan), dim3(SCAN_T), 0, stream, deg, rowptr, blocksum, NN);
  hipLaunchKernelGGL(k_scan_b, dim3(1), dim3(128), 0, stream, blocksum, nb_scan);
  hipLaunchKernelGGL(k_scan_c, dim3(nb_scan), dim3(SCAN_T), 0, stream, deg, rowptr, blocksum,
                     cursor, dis, invc, NN, NE);
  hipLaunchKernelGGL(k_fill, dim3((NE + 255) / 256), dim3(256), 0, stream, src, dst, ea, cursor,
                     csrc, cea, NE);

  dim3 gemm_grid((NN + 31) / 32), tb(256);
  dim3 node_grid((NN + 3) / 4);

  // Layer 0: x -> B1(xw) -> B2(h) -> B1(out, relu+LN)
  hipLaunchKernelGGL((k_gemm<128>), gemm_grid, tb, 0, stream, x, gw0, B1, NN);
  hipLaunchKernelGGL((k_agg<128>), node_grid, tb, 0, stream, B1, dis, rowptr, csrc, gb0, B2, NN);
  hipLaunchKernelGGL((k_msg<128, true>), node_grid, tb, 0, stream, B2, ew0, eb0, rowptr, csrc,
                     cea, invc, lg0, lb0, B1, NN);
  // Layer 1: B1 -> B2(xw) -> B1(h) -> B2(out, relu+LN)
  hipLaunchKernelGGL((k_gemm<128>), gemm_grid, tb, 0, stream, B1, gw1, B2, NN);
  hipLaunchKernelGGL((k_agg<128>), node_grid, tb, 0, stream, B2, dis, rowptr, csrc, gb1, B1, NN);
  hipLaunchKernelGGL((k_msg<128, true>), node_grid, tb, 0, stream, B1, ew1, eb1, rowptr, csrc,
                     cea, invc, lg1, lb1, B2, NN);
  // Layer 2: B2 -> B1(xw,64) -> B2(h,64) -> d_out
  hipLaunchKernelGGL((k_gemm<64>), gemm_grid, tb, 0, stream, B2, gw2, B1, NN);
  hipLaunchKernelGGL((k_agg<64>), node_grid, tb, 0, stream, B1, dis, rowptr, csrc, gb2, B2, NN);
  hipLaunchKernelGGL((k_msg<64, false>), node_grid, tb, 0, stream, B2, ew2, eb2, rowptr, csrc,
                     cea, invc, nullptr, nullptr, out, NN);
  // Pool
  hipLaunchKernelGGL(k_pool, dim3(NG), tb, 0, stream, out, batch, out + (size_t)NN * 64, NN);
}

// Round 2
// 671.330 us; speedup vs baseline: 2.7260x; 2.7260x over previous
//
#include <hip/hip_runtime.h>

#define NN 50000
#define NE 800000
#define NG 64
#define FIN0 128
#define HID 128
#define DOUT 64
#define LN_EPS 1e-5f
#define SCAN_T 512

// ---------------- CSR build ----------------
__global__ __launch_bounds__(256) void k_zero_int(int* p, int n) {
  int i = blockIdx.x * 256 + threadIdx.x;
  if (i < n) p[i] = 0;
}

__global__ __launch_bounds__(256) void k_deg(const int* __restrict__ dst,
                                             int* __restrict__ deg, int e) {
  int i = blockIdx.x * 256 + threadIdx.x;
  if (i < e) atomicAdd(&deg[dst[i]], 1);
}

__global__ __launch_bounds__(SCAN_T) void k_scan_a(const int* __restrict__ deg,
                                                   int* __restrict__ rowptr,
                                                   int* __restrict__ blocksum, int n) {
  __shared__ int s[SCAN_T];
  int t = threadIdx.x, b = blockIdx.x, i = b * SCAN_T + t;
  int v = (i < n) ? deg[i] : 0;
  s[t] = v;
  __syncthreads();
  for (int off = 1; off < SCAN_T; off <<= 1) {
    int x = (t >= off) ? s[t - off] : 0;
    __syncthreads();
    s[t] += x;
    __syncthreads();
  }
  if (i < n) rowptr[i] = s[t] - v;  // exclusive
  if (t == SCAN_T - 1) blocksum[b] = s[t];
}

__global__ __launch_bounds__(128) void k_scan_b(int* __restrict__ blocksum, int nb) {
  __shared__ int s[128];
  int t = threadIdx.x;
  int v = (t < nb) ? blocksum[t] : 0;
  s[t] = v;
  __syncthreads();
  for (int off = 1; off < 128; off <<= 1) {
    int x = (t >= off) ? s[t - off] : 0;
    __syncthreads();
    s[t] += x;
    __syncthreads();
  }
  if (t < nb) blocksum[t] = s[t] - v;  // exclusive
}

__global__ __launch_bounds__(SCAN_T) void k_scan_c(const int* __restrict__ deg,
                                                   int* __restrict__ rowptr,
                                                   const int* __restrict__ blocksum,
                                                   int* __restrict__ cursor,
                                                   float* __restrict__ dis,
                                                   float* __restrict__ invc, int n, int e) {
  int t = threadIdx.x, b = blockIdx.x;
  int i = b * SCAN_T + t;
  if (i < n) {
    int r = rowptr[i] + blocksum[b];
    rowptr[i] = r;
    cursor[i] = r;
    int d = deg[i];
    dis[i] = rsqrtf((float)(d + 1));
    invc[i] = (d > 0) ? 1.0f / (float)d : 1.0f;
  }
  if (i == 0) rowptr[n] = e;
}

__global__ __launch_bounds__(256) void k_fill(const int* __restrict__ src,
                                              const int* __restrict__ dst,
                                              const float* __restrict__ ea,
                                              int* __restrict__ cursor,
                                              int* __restrict__ csrc,
                                              float* __restrict__ cea, int e) {
  int i = blockIdx.x * 256 + threadIdx.x;
  if (i < e) {
    int d = dst[i];
    int pos = atomicAdd(&cursor[d], 1);
    csrc[pos] = src[i];
    cea[pos] = ea[i];
  }
}

// ---------------- GEMM: Y[n,FOUT] = X[n,128] @ W[128,FOUT] ----------------
// 32 rows/block, thread tile = RPT rows x 4 cols. Small register tile +
// bounded unroll: the previous version (8x2 tile, full k-unroll) hit
// VGPR=256 and spilled ~1 GB of scratch traffic per dispatch.
template <int FOUT>
__global__ __launch_bounds__(256) void k_gemm(const float* __restrict__ X,
                                              const float* __restrict__ W,
                                              float* __restrict__ Y, int n) {
  const int FI = 128;
  __shared__ __align__(16) float xs[32][FI];
  int t = threadIdx.x;
  int row0 = blockIdx.x * 32;
  for (int i = t; i < 32 * FI / 4; i += 256) {
    int r = i / (FI / 4);
    int c = i % (FI / 4);
    float4 v = make_float4(0.f, 0.f, 0.f, 0.f);
    if (row0 + r < n) v = ((const float4*)(X + (size_t)(row0 + r) * FI))[c];
    ((float4*)xs[r])[c] = v;
  }
  __syncthreads();
  const int CG = FOUT / 4;   // col-quad groups: 32 (F=128) or 16 (F=64)
  const int RG = 256 / CG;   // row groups: 8 or 16
  const int RPT = 32 / RG;   // rows per thread: 4 or 2
  int cg = t % CG;
  int rg = t / CG;
  float acc[RPT][4];
#pragma unroll
  for (int r = 0; r < RPT; r++)
#pragma unroll
    for (int c = 0; c < 4; c++) acc[r][c] = 0.f;

#pragma unroll 2
  for (int k4 = 0; k4 < FI / 4; k4++) {
    float4 wv[4];
#pragma unroll
    for (int kk = 0; kk < 4; kk++)
      wv[kk] = ((const float4*)(W + (size_t)(4 * k4 + kk) * FOUT))[cg];
#pragma unroll
    for (int r = 0; r < RPT; r++) {
      float4 xv = ((const float4*)xs[rg * RPT + r])[k4];
      acc[r][0] += xv.x * wv[0].x + xv.y * wv[1].x + xv.z * wv[2].x + xv.w * wv[3].x;
      acc[r][1] += xv.x * wv[0].y + xv.y * wv[1].y + xv.z * wv[2].y + xv.w * wv[3].y;
      acc[r][2] += xv.x * wv[0].z + xv.y * wv[1].z + xv.z * wv[2].z + xv.w * wv[3].z;
      acc[r][3] += xv.x * wv[0].w + xv.y * wv[1].w + xv.z * wv[2].w + xv.w * wv[3].w;
    }
  }
#pragma unroll
  for (int r = 0; r < RPT; r++) {
    int row = row0 + rg * RPT + r;
    if (row < n) {
      float4 o = {acc[r][0], acc[r][1], acc[r][2], acc[r][3]};
      ((float4*)(Y + (size_t)row * FOUT))[cg] = o;
    }
  }
}

// ---------------- GCN aggregation: H = agg + dis^2*XW + bias ----------------
template <int F>
__global__ __launch_bounds__(256) void k_agg(const float* __restrict__ XW,
                                             const float* __restrict__ dis,
                                             const int* __restrict__ rowptr,
                                             const int* __restrict__ csrc,
                                             const float* __restrict__ bias,
                                             float* __restrict__ H, int n) {
  int lane = threadIdx.x & 63;
  int node = blockIdx.x * 4 + (threadIdx.x >> 6);
  if (node >= n) return;
  float dn = dis[node];
  int beg = rowptr[node], end = rowptr[node + 1];
  if (F == 128) {
    const float2* xw2 = (const float2*)XW;
    float2 acc = {0.f, 0.f};
    int i = beg;
    for (; i + 4 <= end; i += 4) {
      int s0 = csrc[i], s1 = csrc[i + 1], s2 = csrc[i + 2], s3 = csrc[i + 3];
      float n0 = dn * dis[s0], n1 = dn * dis[s1], n2 = dn * dis[s2], n3 = dn * dis[s3];
      float2 v0 = xw2[(size_t)s0 * 64 + lane];
      float2 v1 = xw2[(size_t)s1 * 64 + lane];
      float2 v2 = xw2[(size_t)s2 * 64 + lane];
      float2 v3 = xw2[(size_t)s3 * 64 + lane];
      acc.x += n0 * v0.x + n1 * v1.x + n2 * v2.x + n3 * v3.x;
      acc.y += n0 * v0.y + n1 * v1.y + n2 * v2.y + n3 * v3.y;
    }
    for (; i < end; i++) {
      int s = csrc[i];
      float nr = dn * dis[s];
      float2 v = xw2[(size_t)s * 64 + lane];
      acc.x += nr * v.x;
      acc.y += nr * v.y;
    }
    float2 self = xw2[(size_t)node * 64 + lane];
    float2 bb = ((const float2*)bias)[lane];
    float d2 = dn * dn;
    float2 h = {acc.x + d2 * self.x + bb.x, acc.y + d2 * self.y + bb.y};
    ((float2*)H)[(size_t)node * 64 + lane] = h;
  } else {
    float acc = 0.f;
    int i = beg;
    for (; i + 4 <= end; i += 4) {
      int s0 = csrc[i], s1 = csrc[i + 1], s2 = csrc[i + 2], s3 = csrc[i + 3];
      float n0 = dn * dis[s0], n1 = dn * dis[s1], n2 = dn * dis[s2], n3 = dn * dis[s3];
      acc += n0 * XW[(size_t)s0 * F + lane] + n1 * XW[(size_t)s1 * F + lane] +
             n2 * XW[(size_t)s2 * F + lane] + n3 * XW[(size_t)s3 * F + lane];
    }
    for (; i < end; i++) {
      int s = csrc[i];
      acc += dn * dis[s] * XW[(size_t)s * F + lane];
    }
    float d2 = dn * dn;
    H[(size_t)node * F + lane] = acc + d2 * XW[(size_t)node * F + lane] + bias[lane];
  }
}

// ------- mean-aggregation of h[src]+relu(ea*ew+eb), optional ReLU+LN -------
template <int F, bool DO_LN>
__global__ __launch_bounds__(256) void k_msg(const float* __restrict__ H,
                                             const float* __restrict__ ew,
                                             const float* __restrict__ eb,
                                             const int* __restrict__ rowptr,
                                             const int* __restrict__ csrc,
                                             const float* __restrict__ cea,
                                             const float* __restrict__ invc,
                                             const float* __restrict__ lng,
                                             const float* __restrict__ lnb,
                                             float* __restrict__ OUT, int n) {
  int lane = threadIdx.x & 63;
  int node = blockIdx.x * 4 + (threadIdx.x >> 6);
  if (node >= n) return;
  int beg = rowptr[node], end = rowptr[node + 1];
  if (F == 128) {
    const float2* h2 = (const float2*)H;
    float2 w = ((const float2*)ew)[lane];
    float2 b = ((const float2*)eb)[lane];
    float2 acc = {0.f, 0.f};
    int i = beg;
    for (; i + 4 <= end; i += 4) {
      int s0 = csrc[i], s1 = csrc[i + 1], s2 = csrc[i + 2], s3 = csrc[i + 3];
      float a0 = cea[i], a1 = cea[i + 1], a2 = cea[i + 2], a3 = cea[i + 3];
      float2 v0 = h2[(size_t)s0 * 64 + lane];
      float2 v1 = h2[(size_t)s1 * 64 + lane];
      float2 v2 = h2[(size_t)s2 * 64 + lane];
      float2 v3 = h2[(size_t)s3 * 64 + lane];
      acc.x += v0.x + fmaxf(a0 * w.x + b.x, 0.f) + v1.x + fmaxf(a1 * w.x + b.x, 0.f) +
               v2.x + fmaxf(a2 * w.x + b.x, 0.f) + v3.x + fmaxf(a3 * w.x + b.x, 0.f);
      acc.y += v0.y + fmaxf(a0 * w.y + b.y, 0.f) + v1.y + fmaxf(a1 * w.y + b.y, 0.f) +
               v2.y + fmaxf(a2 * w.y + b.y, 0.f) + v3.y + fmaxf(a3 * w.y + b.y, 0.f);
    }
    for (; i < end; i++) {
      int s = csrc[i];
      float a = cea[i];
      float2 v = h2[(size_t)s * 64 + lane];
      acc.x += v.x + fmaxf(a * w.x + b.x, 0.f);
      acc.y += v.y + fmaxf(a * w.y + b.y, 0.f);
    }
    float ic = invc[node];
    float2 o = {acc.x * ic, acc.y * ic};
    if (DO_LN) {
      o.x = fmaxf(o.x, 0.f);
      o.y = fmaxf(o.y, 0.f);
      float s1 = o.x + o.y;
      float s2 = o.x * o.x + o.y * o.y;
      for (int off = 32; off; off >>= 1) {
        s1 += __shfl_xor(s1, off, 64);
        s2 += __shfl_xor(s2, off, 64);
      }
      float mu = s1 * (1.f / 128.f);
      float var = s2 * (1.f / 128.f) - mu * mu;
      float r = rsqrtf(var + LN_EPS);
      float2 g = ((const float2*)lng)[lane];
      float2 bb = ((const float2*)lnb)[lane];
      o.x = (o.x - mu) * r * g.x + bb.x;
      o.y = (o.y - mu) * r * g.y + bb.y;
    }
    ((float2*)OUT)[(size_t)node * 64 + lane] = o;
  } else {
    float w = ew[lane], b = eb[lane];
    float acc = 0.f;
    int i = beg;
    for (; i + 4 <= end; i += 4) {
      int s0 = csrc[i], s1 = csrc[i + 1], s2 = csrc[i + 2], s3 = csrc[i + 3];
      float a0 = cea[i], a1 = cea[i + 1], a2 = cea[i + 2], a3 = cea[i + 3];
      acc += H[(size_t)s0 * F + lane] + fmaxf(a0 * w + b, 0.f) +
             H[(size_t)s1 * F + lane] + fmaxf(a1 * w + b, 0.f) +
             H[(size_t)s2 * F + lane] + fmaxf(a2 * w + b, 0.f) +
             H[(size_t)s3 * F + lane] + fmaxf(a3 * w + b, 0.f);
    }
    for (; i < end; i++) {
      int s = csrc[i];
      acc += H[(size_t)s * F + lane] + fmaxf(cea[i] * w + b, 0.f);
    }
    OUT[(size_t)node * F + lane] = acc * invc[node];
  }
}

// ---------------- global mean pool (batch sorted) ----------------
__global__ __launch_bounds__(256) void k_pool(const float* __restrict__ H,
                                              const int* __restrict__ batch,
                                              float* __restrict__ Z, int n) {
  int g = blockIdx.x;
  __shared__ int sbeg, send;
  __shared__ float part[4][64];
  if (threadIdx.x == 0) {
    int lo = 0, hi = n;
    while (lo < hi) { int m = (lo + hi) >> 1; if (batch[m] < g) lo = m + 1; else hi = m; }
    sbeg = lo;
    lo = 0; hi = n;
    while (lo < hi) { int m = (lo + hi) >> 1; if (batch[m] < g + 1) lo = m + 1; else hi = m; }
    send = lo;
  }
  __syncthreads();
  int beg = sbeg, end = send;
  int lane = threadIdx.x & 63, wv = threadIdx.x >> 6;
  float acc = 0.f;
  for (int i = beg + wv; i < end; i += 4) acc += H[(size_t)i * 64 + lane];
  part[wv][lane] = acc;
  __syncthreads();
  if (wv == 0) {
    float s = part[0][lane] + part[1][lane] + part[2][lane] + part[3][lane];
    float c = (float)(end - beg);
    if (c < 1.f) c = 1.f;
    Z[g * 64 + lane] = s / c;
  }
}

extern "C" void kernel_launch(void* const* d_in, const int* in_sizes, int n_in,
                              void* d_out, int out_size, void* d_ws, size_t ws_size,
                              hipStream_t stream) {
  const float* x = (const float*)d_in[0];
  const int* ei = (const int*)d_in[1];
  const float* ea = (const float*)d_in[2];
  const int* batch = (const int*)d_in[3];
  const float* gw0 = (const float*)d_in[4];
  const float* gb0 = (const float*)d_in[5];
  const float* ew0 = (const float*)d_in[6];
  const float* eb0 = (const float*)d_in[7];
  const float* lg0 = (const float*)d_in[8];
  const float* lb0 = (const float*)d_in[9];
  const float* gw1 = (const float*)d_in[10];
  const float* gb1 = (const float*)d_in[11];
  const float* ew1 = (const float*)d_in[12];
  const float* eb1 = (const float*)d_in[13];
  const float* lg1 = (const float*)d_in[14];
  const float* lb1 = (const float*)d_in[15];
  const float* gw2 = (const float*)d_in[16];
  const float* gb2 = (const float*)d_in[17];
  const float* ew2 = (const float*)d_in[18];
  const float* eb2 = (const float*)d_in[19];
  float* out = (float*)d_out;

  const int* src = ei;
  const int* dst = ei + NE;

  char* w = (char*)d_ws;
  size_t off = 0;
  auto alloc = [&](size_t bytes) -> void* {
    void* p = (void*)(w + off);
    off = (off + bytes + 255) & ~(size_t)255;
    return p;
  };
  int* deg = (int*)alloc(NN * sizeof(int));
  int* rowptr = (int*)alloc((NN + 1) * sizeof(int));
  int* blocksum = (int*)alloc(128 * sizeof(int));
  int* cursor = (int*)alloc(NN * sizeof(int));
  int* csrc = (int*)alloc(NE * sizeof(int));
  float* cea = (float*)alloc(NE * sizeof(float));
  float* dis = (float*)alloc(NN * sizeof(float));
  float* invc = (float*)alloc(NN * sizeof(float));
  float* B1 = (float*)alloc((size_t)NN * 128 * sizeof(float));
  float* B2 = (float*)alloc((size_t)NN * 128 * sizeof(float));

  const int nb_scan = (NN + SCAN_T - 1) / SCAN_T;  // 98

  hipLaunchKernelGGL(k_zero_int, dim3((NN + 255) / 256), dim3(256), 0, stream, deg, NN);
  hipLaunchKernelGGL(k_deg, dim3((NE + 255) / 256), dim3(256), 0, stream, dst, deg, NE);
  hipLaunchKernelGGL(k_scan_a, dim3(nb_scan), dim3(SCAN_T), 0, stream, deg, rowptr, blocksum, NN);
  hipLaunchKernelGGL(k_scan_b, dim3(1), dim3(128), 0, stream, blocksum, nb_scan);
  hipLaunchKernelGGL(k_scan_c, dim3(nb_scan), dim3(SCAN_T), 0, stream, deg, rowptr, blocksum,
                     cursor, dis, invc, NN, NE);
  hipLaunchKernelGGL(k_fill, dim3((NE + 255) / 256), dim3(256), 0, stream, src, dst, ea, cursor,
                     csrc, cea, NE);

  dim3 gemm_grid((NN + 31) / 32), tb(256);
  dim3 node_grid((NN + 3) / 4);

  // Layer 0: x -> B1(xw) -> B2(h) -> B1(out, relu+LN)
  hipLaunchKernelGGL((k_gemm<128>), gemm_grid, tb, 0, stream, x, gw0, B1, NN);
  hipLaunchKernelGGL((k_agg<128>), node_grid, tb, 0, stream, B1, dis, rowptr, csrc, gb0, B2, NN);
  hipLaunchKernelGGL((k_msg<128, true>), node_grid, tb, 0, stream, B2, ew0, eb0, rowptr, csrc,
                     cea, invc, lg0, lb0, B1, NN);
  // Layer 1: B1 -> B2(xw) -> B1(h) -> B2(out, relu+LN)
  hipLaunchKernelGGL((k_gemm<128>), gemm_grid, tb, 0, stream, B1, gw1, B2, NN);
  hipLaunchKernelGGL((k_agg<128>), node_grid, tb, 0, stream, B2, dis, rowptr, csrc, gb1, B1, NN);
  hipLaunchKernelGGL((k_msg<128, true>), node_grid, tb, 0, stream, B1, ew1, eb1, rowptr, csrc,
                     cea, invc, lg1, lb1, B2, NN);
  // Layer 2: B2 -> B1(xw,64) -> B2(h,64) -> d_out
  hipLaunchKernelGGL((k_gemm<64>), gemm_grid, tb, 0, stream, B2, gw2, B1, NN);
  hipLaunchKernelGGL((k_agg<64>), node_grid, tb, 0, stream, B1, dis, rowptr, csrc, gb2, B2, NN);
  hipLaunchKernelGGL((k_msg<64, false>), node_grid, tb, 0, stream, B2, ew2, eb2, rowptr, csrc,
                     cea, invc, nullptr, nullptr, out, NN);
  // Pool
  hipLaunchKernelGGL(k_pool, dim3(NG), tb, 0, stream, out, batch, out + (size_t)NN * 64, NN);
}

// Round 3
// 594.239 us; speedup vs baseline: 3.0797x; 1.1297x over previous
//
#include <hip/hip_runtime.h>

#define NN 50000
#define NE 800000
#define NG 64
#define HID 128
#define DOUT 64
#define LN_EPS 1e-5f
#define SCAN_T 512

typedef unsigned int uint32;
typedef unsigned short ushort16;

// ---- bf16 helpers (RNE pack, cheap unpack) ----
__device__ inline ushort16 f2bf(float f) {
  uint32 u = __float_as_uint(f);
  u += 0x7fffu + ((u >> 16) & 1u);
  return (ushort16)(u >> 16);
}
__device__ inline uint32 pack2(float x, float y) {
  return (uint32)f2bf(x) | ((uint32)f2bf(y) << 16);
}
__device__ inline float bflo(uint32 p) { return __uint_as_float(p << 16); }
__device__ inline float bfhi(uint32 p) { return __uint_as_float(p & 0xffff0000u); }

// ---------------- CSR build ----------------
__global__ __launch_bounds__(256) void k_zero_int(int* p, int n) {
  int i = blockIdx.x * 256 + threadIdx.x;
  if (i < n) p[i] = 0;
}

__global__ __launch_bounds__(256) void k_deg(const int* __restrict__ dst,
                                             int* __restrict__ deg, int e) {
  int i = blockIdx.x * 256 + threadIdx.x;
  if (i < e) atomicAdd(&deg[dst[i]], 1);
}

__global__ __launch_bounds__(SCAN_T) void k_scan_a(const int* __restrict__ deg,
                                                   int* __restrict__ rowptr,
                                                   int* __restrict__ blocksum, int n) {
  __shared__ int s[SCAN_T];
  int t = threadIdx.x, b = blockIdx.x, i = b * SCAN_T + t;
  int v = (i < n) ? deg[i] : 0;
  s[t] = v;
  __syncthreads();
  for (int off = 1; off < SCAN_T; off <<= 1) {
    int x = (t >= off) ? s[t - off] : 0;
    __syncthreads();
    s[t] += x;
    __syncthreads();
  }
  if (i < n) rowptr[i] = s[t] - v;  // exclusive
  if (t == SCAN_T - 1) blocksum[b] = s[t];
}

__global__ __launch_bounds__(128) void k_scan_b(int* __restrict__ blocksum, int nb) {
  __shared__ int s[128];
  int t = threadIdx.x;
  int v = (t < nb) ? blocksum[t] : 0;
  s[t] = v;
  __syncthreads();
  for (int off = 1; off < 128; off <<= 1) {
    int x = (t >= off) ? s[t - off] : 0;
    __syncthreads();
    s[t] += x;
    __syncthreads();
  }
  if (t < nb) blocksum[t] = s[t] - v;  // exclusive
}

__global__ __launch_bounds__(SCAN_T) void k_scan_c(const int* __restrict__ deg,
                                                   int* __restrict__ rowptr,
                                                   const int* __restrict__ blocksum,
                                                   int* __restrict__ cursor,
                                                   float* __restrict__ dis,
                                                   float* __restrict__ invc, int n, int e) {
  int t = threadIdx.x, b = blockIdx.x;
  int i = b * SCAN_T + t;
  if (i < n) {
    int r = rowptr[i] + blocksum[b];
    rowptr[i] = r;
    cursor[i] = r;
    int d = deg[i];
    dis[i] = rsqrtf((float)(d + 1));
    invc[i] = (d > 0) ? 1.0f / (float)d : 1.0f;
  }
  if (i == 0) rowptr[n] = e;
}

__global__ __launch_bounds__(256) void k_fill(const int* __restrict__ src,
                                              const int* __restrict__ dst,
                                              const float* __restrict__ ea,
                                              int* __restrict__ cursor,
                                              int* __restrict__ csrc,
                                              float* __restrict__ cea, int e) {
  int i = blockIdx.x * 256 + threadIdx.x;
  if (i < e) {
    int d = dst[i];
    int pos = atomicAdd(&cursor[d], 1);
    csrc[pos] = src[i];
    cea[pos] = ea[i];
  }
}

// ---------------- GEMM: Y[n,FOUT] = X[n,128] @ W[128,FOUT] ----------------
// 32 rows/block, thread tile = RPT rows x 4 cols, bounded k-unroll (VGPR-safe).
// IN_BF: X is packed bf16; OUT_BF: Y written as packed bf16.
template <int FOUT, bool IN_BF, bool OUT_BF>
__global__ __launch_bounds__(256) void k_gemm(const void* __restrict__ Xv,
                                              const float* __restrict__ W,
                                              void* __restrict__ Yv, int n) {
  const int FI = 128;
  __shared__ __align__(16) float xs[32][FI];
  int t = threadIdx.x;
  int row0 = blockIdx.x * 32;
  if (IN_BF) {
    const ushort16* Xb = (const ushort16*)Xv;
    for (int i = t; i < 32 * 32; i += 256) {
      int r = i >> 5, c = i & 31;
      uint2 v = make_uint2(0u, 0u);
      if (row0 + r < n) v = ((const uint2*)(Xb + (size_t)(row0 + r) * FI))[c];
      float4 f = {bflo(v.x), bfhi(v.x), bflo(v.y), bfhi(v.y)};
      ((float4*)xs[r])[c] = f;
    }
  } else {
    const float* X = (const float*)Xv;
    for (int i = t; i < 32 * FI / 4; i += 256) {
      int r = i / (FI / 4);
      int c = i % (FI / 4);
      float4 v = make_float4(0.f, 0.f, 0.f, 0.f);
      if (row0 + r < n) v = ((const float4*)(X + (size_t)(row0 + r) * FI))[c];
      ((float4*)xs[r])[c] = v;
    }
  }
  __syncthreads();
  const int CG = FOUT / 4;   // col-quad groups: 32 (F=128) or 16 (F=64)
  const int RG = 256 / CG;   // row groups: 8 or 16
  const int RPT = 32 / RG;   // rows per thread: 4 or 2
  int cg = t % CG;
  int rg = t / CG;
  float acc[RPT][4];
#pragma unroll
  for (int r = 0; r < RPT; r++)
#pragma unroll
    for (int c = 0; c < 4; c++) acc[r][c] = 0.f;

#pragma unroll 2
  for (int k4 = 0; k4 < FI / 4; k4++) {
    float4 wv[4];
#pragma unroll
    for (int kk = 0; kk < 4; kk++)
      wv[kk] = ((const float4*)(W + (size_t)(4 * k4 + kk) * FOUT))[cg];
#pragma unroll
    for (int r = 0; r < RPT; r++) {
      float4 xv = ((const float4*)xs[rg * RPT + r])[k4];
      acc[r][0] += xv.x * wv[0].x + xv.y * wv[1].x + xv.z * wv[2].x + xv.w * wv[3].x;
      acc[r][1] += xv.x * wv[0].y + xv.y * wv[1].y + xv.z * wv[2].y + xv.w * wv[3].y;
      acc[r][2] += xv.x * wv[0].z + xv.y * wv[1].z + xv.z * wv[2].z + xv.w * wv[3].z;
      acc[r][3] += xv.x * wv[0].w + xv.y * wv[1].w + xv.z * wv[2].w + xv.w * wv[3].w;
    }
  }
#pragma unroll
  for (int r = 0; r < RPT; r++) {
    int row = row0 + rg * RPT + r;
    if (row < n) {
      if (OUT_BF) {
        uint2 o = {pack2(acc[r][0], acc[r][1]), pack2(acc[r][2], acc[r][3])};
        ((uint2*)((ushort16*)Yv + (size_t)row * FOUT))[cg] = o;
      } else {
        float4 o = {acc[r][0], acc[r][1], acc[r][2], acc[r][3]};
        ((float4*)((float*)Yv + (size_t)row * FOUT))[cg] = o;
      }
    }
  }
}

// ------- GCN aggregation, bf16 tables (F=128): H = agg + dis^2*XW + b -------
// lane covers features {2*lane, 2*lane+1}; one uint (2 bf16) per gather.
__global__ __launch_bounds__(256) void k_agg_bf(const uint32* __restrict__ XWb,
                                                const float* __restrict__ dis,
                                                const int* __restrict__ rowptr,
                                                const int* __restrict__ csrc,
                                                const float* __restrict__ bias,
                                                uint32* __restrict__ Hb, int n) {
  int lane = threadIdx.x & 63;
  int node = blockIdx.x * 4 + (threadIdx.x >> 6);
  if (node >= n) return;
  float dn = dis[node];
  int beg = rowptr[node], end = rowptr[node + 1];
  float ax = 0.f, ay = 0.f;
  int i = beg;
  for (; i + 4 <= end; i += 4) {
    int s0 = csrc[i], s1 = csrc[i + 1], s2 = csrc[i + 2], s3 = csrc[i + 3];
    float n0 = dn * dis[s0], n1 = dn * dis[s1], n2 = dn * dis[s2], n3 = dn * dis[s3];
    uint32 p0 = XWb[(size_t)s0 * 64 + lane];
    uint32 p1 = XWb[(size_t)s1 * 64 + lane];
    uint32 p2 = XWb[(size_t)s2 * 64 + lane];
    uint32 p3 = XWb[(size_t)s3 * 64 + lane];
    ax += n0 * bflo(p0) + n1 * bflo(p1) + n2 * bflo(p2) + n3 * bflo(p3);
    ay += n0 * bfhi(p0) + n1 * bfhi(p1) + n2 * bfhi(p2) + n3 * bfhi(p3);
  }
  for (; i < end; i++) {
    int s = csrc[i];
    float nr = dn * dis[s];
    uint32 p = XWb[(size_t)s * 64 + lane];
    ax += nr * bflo(p);
    ay += nr * bfhi(p);
  }
  uint32 ps = XWb[(size_t)node * 64 + lane];
  float2 bb = ((const float2*)bias)[lane];
  float d2 = dn * dn;
  float hx = ax + d2 * bflo(ps) + bb.x;
  float hy = ay + d2 * bfhi(ps) + bb.y;
  Hb[(size_t)node * 64 + lane] = pack2(hx, hy);
}

// -- mean-agg of h[src]+relu(ea*ew+eb), ReLU+LN epilogue, bf16 tables (F=128) --
__global__ __launch_bounds__(256) void k_msg_bf(const uint32* __restrict__ Hb,
                                                const float* __restrict__ ew,
                                                const float* __restrict__ eb,
                                                const int* __restrict__ rowptr,
                                                const int* __restrict__ csrc,
                                                const float* __restrict__ cea,
                                                const float* __restrict__ invc,
                                                const float* __restrict__ lng,
                                                const float* __restrict__ lnb,
                                                uint32* __restrict__ OUTb, int n) {
  int lane = threadIdx.x & 63;
  int node = blockIdx.x * 4 + (threadIdx.x >> 6);
  if (node >= n) return;
  int beg = rowptr[node], end = rowptr[node + 1];
  float2 w = ((const float2*)ew)[lane];
  float2 b = ((const float2*)eb)[lane];
  float ax = 0.f, ay = 0.f;
  int i = beg;
  for (; i + 4 <= end; i += 4) {
    int s0 = csrc[i], s1 = csrc[i + 1], s2 = csrc[i + 2], s3 = csrc[i + 3];
    float a0 = cea[i], a1 = cea[i + 1], a2 = cea[i + 2], a3 = cea[i + 3];
    uint32 p0 = Hb[(size_t)s0 * 64 + lane];
    uint32 p1 = Hb[(size_t)s1 * 64 + lane];
    uint32 p2 = Hb[(size_t)s2 * 64 + lane];
    uint32 p3 = Hb[(size_t)s3 * 64 + lane];
    ax += bflo(p0) + fmaxf(a0 * w.x + b.x, 0.f) + bflo(p1) + fmaxf(a1 * w.x + b.x, 0.f) +
          bflo(p2) + fmaxf(a2 * w.x + b.x, 0.f) + bflo(p3) + fmaxf(a3 * w.x + b.x, 0.f);
    ay += bfhi(p0) + fmaxf(a0 * w.y + b.y, 0.f) + bfhi(p1) + fmaxf(a1 * w.y + b.y, 0.f) +
          bfhi(p2) + fmaxf(a2 * w.y + b.y, 0.f) + bfhi(p3) + fmaxf(a3 * w.y + b.y, 0.f);
  }
  for (; i < end; i++) {
    int s = csrc[i];
    float a = cea[i];
    uint32 p = Hb[(size_t)s * 64 + lane];
    ax += bflo(p) + fmaxf(a * w.x + b.x, 0.f);
    ay += bfhi(p) + fmaxf(a * w.y + b.y, 0.f);
  }
  float ic = invc[node];
  float ox = fmaxf(ax * ic, 0.f);
  float oy = fmaxf(ay * ic, 0.f);
  float s1 = ox + oy;
  float s2 = ox * ox + oy * oy;
  for (int off = 32; off; off >>= 1) {
    s1 += __shfl_xor(s1, off, 64);
    s2 += __shfl_xor(s2, off, 64);
  }
  float mu = s1 * (1.f / 128.f);
  float var = s2 * (1.f / 128.f) - mu * mu;
  float r = rsqrtf(var + LN_EPS);
  float2 g = ((const float2*)lng)[lane];
  float2 bb = ((const float2*)lnb)[lane];
  ox = (ox - mu) * r * g.x + bb.x;
  oy = (oy - mu) * r * g.y + bb.y;
  OUTb[(size_t)node * 64 + lane] = pack2(ox, oy);
}

// ---------------- fp32 layer-2 kernels (F=64, output precision) ----------------
__global__ __launch_bounds__(256) void k_agg64(const float* __restrict__ XW,
                                               const float* __restrict__ dis,
                                               const int* __restrict__ rowptr,
                                               const int* __restrict__ csrc,
                                               const float* __restrict__ bias,
                                               float* __restrict__ H, int n) {
  int lane = threadIdx.x & 63;
  int node = blockIdx.x * 4 + (threadIdx.x >> 6);
  if (node >= n) return;
  float dn = dis[node];
  int beg = rowptr[node], end = rowptr[node + 1];
  float acc = 0.f;
  int i = beg;
  for (; i + 4 <= end; i += 4) {
    int s0 = csrc[i], s1 = csrc[i + 1], s2 = csrc[i + 2], s3 = csrc[i + 3];
    float n0 = dn * dis[s0], n1 = dn * dis[s1], n2 = dn * dis[s2], n3 = dn * dis[s3];
    acc += n0 * XW[(size_t)s0 * 64 + lane] + n1 * XW[(size_t)s1 * 64 + lane] +
           n2 * XW[(size_t)s2 * 64 + lane] + n3 * XW[(size_t)s3 * 64 + lane];
  }
  for (; i < end; i++) {
    int s = csrc[i];
    acc += dn * dis[s] * XW[(size_t)s * 64 + lane];
  }
  float d2 = dn * dn;
  H[(size_t)node * 64 + lane] = acc + d2 * XW[(size_t)node * 64 + lane] + bias[lane];
}

__global__ __launch_bounds__(256) void k_msg64(const float* __restrict__ H,
                                               const float* __restrict__ ew,
                                               const float* __restrict__ eb,
                                               const int* __restrict__ rowptr,
                                               const int* __restrict__ csrc,
                                               const float* __restrict__ cea,
                                               const float* __restrict__ invc,
                                               float* __restrict__ OUT, int n) {
  int lane = threadIdx.x & 63;
  int node = blockIdx.x * 4 + (threadIdx.x >> 6);
  if (node >= n) return;
  int beg = rowptr[node], end = rowptr[node + 1];
  float w = ew[lane], b = eb[lane];
  float acc = 0.f;
  int i = beg;
  for (; i + 4 <= end; i += 4) {
    int s0 = csrc[i], s1 = csrc[i + 1], s2 = csrc[i + 2], s3 = csrc[i + 3];
    float a0 = cea[i], a1 = cea[i + 1], a2 = cea[i + 2], a3 = cea[i + 3];
    acc += H[(size_t)s0 * 64 + lane] + fmaxf(a0 * w + b, 0.f) +
           H[(size_t)s1 * 64 + lane] + fmaxf(a1 * w + b, 0.f) +
           H[(size_t)s2 * 64 + lane] + fmaxf(a2 * w + b, 0.f) +
           H[(size_t)s3 * 64 + lane] + fmaxf(a3 * w + b, 0.f);
  }
  for (; i < end; i++) {
    int s = csrc[i];
    acc += H[(size_t)s * 64 + lane] + fmaxf(cea[i] * w + b, 0.f);
  }
  OUT[(size_t)node * 64 + lane] = acc * invc[node];
}

// ---------------- global mean pool (batch sorted) ----------------
__global__ __launch_bounds__(256) void k_pool(const float* __restrict__ H,
                                              const int* __restrict__ batch,
                                              float* __restrict__ Z, int n) {
  int g = blockIdx.x;
  __shared__ int sbeg, send;
  __shared__ float part[4][64];
  if (threadIdx.x == 0) {
    int lo = 0, hi = n;
    while (lo < hi) { int m = (lo + hi) >> 1; if (batch[m] < g) lo = m + 1; else hi = m; }
    sbeg = lo;
    lo = 0; hi = n;
    while (lo < hi) { int m = (lo + hi) >> 1; if (batch[m] < g + 1) lo = m + 1; else hi = m; }
    send = lo;
  }
  __syncthreads();
  int beg = sbeg, end = send;
  int lane = threadIdx.x & 63, wv = threadIdx.x >> 6;
  float acc = 0.f;
  for (int i = beg + wv; i < end; i += 4) acc += H[(size_t)i * 64 + lane];
  part[wv][lane] = acc;
  __syncthreads();
  if (wv == 0) {
    float s = part[0][lane] + part[1][lane] + part[2][lane] + part[3][lane];
    float c = (float)(end - beg);
    if (c < 1.f) c = 1.f;
    Z[g * 64 + lane] = s / c;
  }
}

extern "C" void kernel_launch(void* const* d_in, const int* in_sizes, int n_in,
                              void* d_out, int out_size, void* d_ws, size_t ws_size,
                              hipStream_t stream) {
  const float* x = (const float*)d_in[0];
  const int* ei = (const int*)d_in[1];
  const float* ea = (const float*)d_in[2];
  const int* batch = (const int*)d_in[3];
  const float* gw0 = (const float*)d_in[4];
  const float* gb0 = (const float*)d_in[5];
  const float* ew0 = (const float*)d_in[6];
  const float* eb0 = (const float*)d_in[7];
  const float* lg0 = (const float*)d_in[8];
  const float* lb0 = (const float*)d_in[9];
  const float* gw1 = (const float*)d_in[10];
  const float* gb1 = (const float*)d_in[11];
  const float* ew1 = (const float*)d_in[12];
  const float* eb1 = (const float*)d_in[13];
  const float* lg1 = (const float*)d_in[14];
  const float* lb1 = (const float*)d_in[15];
  const float* gw2 = (const float*)d_in[16];
  const float* gb2 = (const float*)d_in[17];
  const float* ew2 = (const float*)d_in[18];
  const float* eb2 = (const float*)d_in[19];
  float* out = (float*)d_out;

  const int* src = ei;
  const int* dst = ei + NE;

  char* w = (char*)d_ws;
  size_t off = 0;
  auto alloc = [&](size_t bytes) -> void* {
    void* p = (void*)(w + off);
    off = (off + bytes + 255) & ~(size_t)255;
    return p;
  };
  int* deg = (int*)alloc(NN * sizeof(int));
  int* rowptr = (int*)alloc((NN + 1) * sizeof(int));
  int* blocksum = (int*)alloc(128 * sizeof(int));
  int* cursor = (int*)alloc(NN * sizeof(int));
  int* csrc = (int*)alloc(NE * sizeof(int));
  float* cea = (float*)alloc(NE * sizeof(float));
  float* dis = (float*)alloc(NN * sizeof(float));
  float* invc = (float*)alloc(NN * sizeof(float));
  uint32* B1b = (uint32*)alloc((size_t)NN * 64 * sizeof(uint32));  // 128 bf16/row
  uint32* B2b = (uint32*)alloc((size_t)NN * 64 * sizeof(uint32));
  float* F1 = (float*)alloc((size_t)NN * 64 * sizeof(float));
  float* F2 = (float*)alloc((size_t)NN * 64 * sizeof(float));

  const int nb_scan = (NN + SCAN_T - 1) / SCAN_T;  // 98

  hipLaunchKernelGGL(k_zero_int, dim3((NN + 255) / 256), dim3(256), 0, stream, deg, NN);
  hipLaunchKernelGGL(k_deg, dim3((NE + 255) / 256), dim3(256), 0, stream, dst, deg, NE);
  hipLaunchKernelGGL(k_scan_a, dim3(nb_scan), dim3(SCAN_T), 0, stream, deg, rowptr, blocksum, NN);
  hipLaunchKernelGGL(k_scan_b, dim3(1), dim3(128), 0, stream, blocksum, nb_scan);
  hipLaunchKernelGGL(k_scan_c, dim3(nb_scan), dim3(SCAN_T), 0, stream, deg, rowptr, blocksum,
                     cursor, dis, invc, NN, NE);
  hipLaunchKernelGGL(k_fill, dim3((NE + 255) / 256), dim3(256), 0, stream, src, dst, ea, cursor,
                     csrc, cea, NE);

  dim3 gemm_grid((NN + 31) / 32), tb(256);
  dim3 node_grid((NN + 3) / 4);

  // Layer 0: x(fp32) -> B1b(xw bf16) -> B2b(h bf16) -> B1b(relu+LN bf16)
  hipLaunchKernelGGL((k_gemm<128, false, true>), gemm_grid, tb, 0, stream, x, gw0, B1b, NN);
  hipLaunchKernelGGL(k_agg_bf, node_grid, tb, 0, stream, B1b, dis, rowptr, csrc, gb0, B2b, NN);
  hipLaunchKernelGGL(k_msg_bf, node_grid, tb, 0, stream, B2b, ew0, eb0, rowptr, csrc, cea, invc,
                     lg0, lb0, B1b, NN);
  // Layer 1: B1b -> B2b(xw) -> B1b(h) -> B2b(relu+LN)
  hipLaunchKernelGGL((k_gemm<128, true, true>), gemm_grid, tb, 0, stream, B1b, gw1, B2b, NN);
  hipLaunchKernelGGL(k_agg_bf, node_grid, tb, 0, stream, B2b, dis, rowptr, csrc, gb1, B1b, NN);
  hipLaunchKernelGGL(k_msg_bf, node_grid, tb, 0, stream, B1b, ew1, eb1, rowptr, csrc, cea, invc,
                     lg1, lb1, B2b, NN);
  // Layer 2 (fp32): B2b -> F1(xw) -> F2(h) -> d_out
  hipLaunchKernelGGL((k_gemm<64, true, false>), gemm_grid, tb, 0, stream, B2b, gw2, F1, NN);
  hipLaunchKernelGGL(k_agg64, node_grid, tb, 0, stream, F1, dis, rowptr, csrc, gb2, F2, NN);
  hipLaunchKernelGGL(k_msg64, node_grid, tb, 0, stream, F2, ew2, eb2, rowptr, csrc, cea, invc,
                     out, NN);
  // Pool
  hipLaunchKernelGGL(k_pool, dim3(NG), tb, 0, stream, out, batch, out + (size_t)NN * 64, NN);
}

// Round 4
// 570.707 us; speedup vs baseline: 3.2067x; 1.0412x over previous
//
#include <hip/hip_runtime.h>

#define NN 50000
#define NE 800000
#define NG 64
#define HID 128
#define DOUT 64
#define LN_EPS 1e-5f
#define SCAN_T 512

typedef unsigned int uint32;
typedef unsigned short ushort16;

// ---- bf16 helpers (RNE pack, cheap unpack) ----
__device__ inline ushort16 f2bf(float f) {
  uint32 u = __float_as_uint(f);
  u += 0x7fffu + ((u >> 16) & 1u);
  return (ushort16)(u >> 16);
}
__device__ inline uint32 pack2(float x, float y) {
  return (uint32)f2bf(x) | ((uint32)f2bf(y) << 16);
}
__device__ inline float bflo(uint32 p) { return __uint_as_float(p << 16); }
__device__ inline float bfhi(uint32 p) { return __uint_as_float(p & 0xffff0000u); }

// ---------------- CSR build ----------------
__global__ __launch_bounds__(256) void k_zero_int(int* p, int n) {
  int i = blockIdx.x * 256 + threadIdx.x;
  if (i < n) p[i] = 0;
}

__global__ __launch_bounds__(256) void k_zero_f(float* p, int n) {
  int i = blockIdx.x * 256 + threadIdx.x;
  if (i < n) p[i] = 0.f;
}

__global__ __launch_bounds__(256) void k_deg(const int* __restrict__ dst,
                                             int* __restrict__ deg, int e) {
  int i = blockIdx.x * 256 + threadIdx.x;
  if (i < e) atomicAdd(&deg[dst[i]], 1);
}

__global__ __launch_bounds__(SCAN_T) void k_scan_a(const int* __restrict__ deg,
                                                   int* __restrict__ rowptr,
                                                   int* __restrict__ blocksum, int n) {
  __shared__ int s[SCAN_T];
  int t = threadIdx.x, b = blockIdx.x, i = b * SCAN_T + t;
  int v = (i < n) ? deg[i] : 0;
  s[t] = v;
  __syncthreads();
  for (int off = 1; off < SCAN_T; off <<= 1) {
    int x = (t >= off) ? s[t - off] : 0;
    __syncthreads();
    s[t] += x;
    __syncthreads();
  }
  if (i < n) rowptr[i] = s[t] - v;  // exclusive
  if (t == SCAN_T - 1) blocksum[b] = s[t];
}

__global__ __launch_bounds__(128) void k_scan_b(int* __restrict__ blocksum, int nb) {
  __shared__ int s[128];
  int t = threadIdx.x;
  int v = (t < nb) ? blocksum[t] : 0;
  s[t] = v;
  __syncthreads();
  for (int off = 1; off < 128; off <<= 1) {
    int x = (t >= off) ? s[t - off] : 0;
    __syncthreads();
    s[t] += x;
    __syncthreads();
  }
  if (t < nb) blocksum[t] = s[t] - v;  // exclusive
}

__global__ __launch_bounds__(SCAN_T) void k_scan_c(const int* __restrict__ deg,
                                                   int* __restrict__ rowptr,
                                                   const int* __restrict__ blocksum,
                                                   int* __restrict__ cursor,
                                                   float* __restrict__ dis,
                                                   float* __restrict__ invc, int n, int e) {
  int t = threadIdx.x, b = blockIdx.x;
  int i = b * SCAN_T + t;
  if (i < n) {
    int r = rowptr[i] + blocksum[b];
    rowptr[i] = r;
    cursor[i] = r;
    int d = deg[i];
    dis[i] = rsqrtf((float)(d + 1));
    invc[i] = (d > 0) ? 1.0f / (float)d : 1.0f;
  }
  if (i == 0) rowptr[n] = e;
}

__global__ __launch_bounds__(256) void k_fill(const int* __restrict__ src,
                                              const int* __restrict__ dst,
                                              const float* __restrict__ ea,
                                              int* __restrict__ cursor,
                                              int* __restrict__ csrc,
                                              float* __restrict__ cea, int e) {
  int i = blockIdx.x * 256 + threadIdx.x;
  if (i < e) {
    int d = dst[i];
    int pos = atomicAdd(&cursor[d], 1);
    csrc[pos] = src[i];
    cea[pos] = ea[i];
  }
}

// ---------------- GEMM: Y[n,FOUT] = X[n,128] @ W[128,FOUT] ----------------
// 32 rows/block, thread tile = RPT rows x 4 cols, bounded k-unroll (VGPR-safe).
// IN_BF: X is packed bf16; OUT_BF: Y written as packed bf16.
template <int FOUT, bool IN_BF, bool OUT_BF>
__global__ __launch_bounds__(256) void k_gemm(const void* __restrict__ Xv,
                                              const float* __restrict__ W,
                                              void* __restrict__ Yv, int n) {
  const int FI = 128;
  __shared__ __align__(16) float xs[32][FI];
  int t = threadIdx.x;
  int row0 = blockIdx.x * 32;
  if (IN_BF) {
    const ushort16* Xb = (const ushort16*)Xv;
    for (int i = t; i < 32 * 32; i += 256) {
      int r = i >> 5, c = i & 31;
      uint2 v = make_uint2(0u, 0u);
      if (row0 + r < n) v = ((const uint2*)(Xb + (size_t)(row0 + r) * FI))[c];
      float4 f = {bflo(v.x), bfhi(v.x), bflo(v.y), bfhi(v.y)};
      ((float4*)xs[r])[c] = f;
    }
  } else {
    const float* X = (const float*)Xv;
    for (int i = t; i < 32 * FI / 4; i += 256) {
      int r = i / (FI / 4);
      int c = i % (FI / 4);
      float4 v = make_float4(0.f, 0.f, 0.f, 0.f);
      if (row0 + r < n) v = ((const float4*)(X + (size_t)(row0 + r) * FI))[c];
      ((float4*)xs[r])[c] = v;
    }
  }
  __syncthreads();
  const int CG = FOUT / 4;   // col-quad groups: 32 (F=128) or 16 (F=64)
  const int RG = 256 / CG;   // row groups: 8 or 16
  const int RPT = 32 / RG;   // rows per thread: 4 or 2
  int cg = t % CG;
  int rg = t / CG;
  float acc[RPT][4];
#pragma unroll
  for (int r = 0; r < RPT; r++)
#pragma unroll
    for (int c = 0; c < 4; c++) acc[r][c] = 0.f;

#pragma unroll 2
  for (int k4 = 0; k4 < FI / 4; k4++) {
    float4 wv[4];
#pragma unroll
    for (int kk = 0; kk < 4; kk++)
      wv[kk] = ((const float4*)(W + (size_t)(4 * k4 + kk) * FOUT))[cg];
#pragma unroll
    for (int r = 0; r < RPT; r++) {
      float4 xv = ((const float4*)xs[rg * RPT + r])[k4];
      acc[r][0] += xv.x * wv[0].x + xv.y * wv[1].x + xv.z * wv[2].x + xv.w * wv[3].x;
      acc[r][1] += xv.x * wv[0].y + xv.y * wv[1].y + xv.z * wv[2].y + xv.w * wv[3].y;
      acc[r][2] += xv.x * wv[0].z + xv.y * wv[1].z + xv.z * wv[2].z + xv.w * wv[3].z;
      acc[r][3] += xv.x * wv[0].w + xv.y * wv[1].w + xv.z * wv[2].w + xv.w * wv[3].w;
    }
  }
#pragma unroll
  for (int r = 0; r < RPT; r++) {
    int row = row0 + rg * RPT + r;
    if (row < n) {
      if (OUT_BF) {
        uint2 o = {pack2(acc[r][0], acc[r][1]), pack2(acc[r][2], acc[r][3])};
        ((uint2*)((ushort16*)Yv + (size_t)row * FOUT))[cg] = o;
      } else {
        float4 o = {acc[r][0], acc[r][1], acc[r][2], acc[r][3]};
        ((float4*)((float*)Yv + (size_t)row * FOUT))[cg] = o;
      }
    }
  }
}

// ------- GCN aggregation, bf16 tables (F=128): H = agg + dis^2*XW + b -------
__global__ __launch_bounds__(256) void k_agg_bf(const uint32* __restrict__ XWb,
                                                const float* __restrict__ dis,
                                                const int* __restrict__ rowptr,
                                                const int* __restrict__ csrc,
                                                const float* __restrict__ bias,
                                                uint32* __restrict__ Hb, int n) {
  int lane = threadIdx.x & 63;
  int node = blockIdx.x * 4 + (threadIdx.x >> 6);
  if (node >= n) return;
  float dn = dis[node];
  int beg = rowptr[node], end = rowptr[node + 1];
  float ax = 0.f, ay = 0.f;
  int i = beg;
  for (; i + 4 <= end; i += 4) {
    int s0 = csrc[i], s1 = csrc[i + 1], s2 = csrc[i + 2], s3 = csrc[i + 3];
    float n0 = dn * dis[s0], n1 = dn * dis[s1], n2 = dn * dis[s2], n3 = dn * dis[s3];
    uint32 p0 = XWb[(size_t)s0 * 64 + lane];
    uint32 p1 = XWb[(size_t)s1 * 64 + lane];
    uint32 p2 = XWb[(size_t)s2 * 64 + lane];
    uint32 p3 = XWb[(size_t)s3 * 64 + lane];
    ax += n0 * bflo(p0) + n1 * bflo(p1) + n2 * bflo(p2) + n3 * bflo(p3);
    ay += n0 * bfhi(p0) + n1 * bfhi(p1) + n2 * bfhi(p2) + n3 * bfhi(p3);
  }
  for (; i < end; i++) {
    int s = csrc[i];
    float nr = dn * dis[s];
    uint32 p = XWb[(size_t)s * 64 + lane];
    ax += nr * bflo(p);
    ay += nr * bfhi(p);
  }
  uint32 ps = XWb[(size_t)node * 64 + lane];
  float2 bb = ((const float2*)bias)[lane];
  float d2 = dn * dn;
  float hx = ax + d2 * bflo(ps) + bb.x;
  float hy = ay + d2 * bfhi(ps) + bb.y;
  Hb[(size_t)node * 64 + lane] = pack2(hx, hy);
}

// -- mean-agg of h[src]+relu(ea*ew+eb), ReLU+LN epilogue, bf16 tables (F=128) --
__global__ __launch_bounds__(256) void k_msg_bf(const uint32* __restrict__ Hb,
                                                const float* __restrict__ ew,
                                                const float* __restrict__ eb,
                                                const int* __restrict__ rowptr,
                                                const int* __restrict__ csrc,
                                                const float* __restrict__ cea,
                                                const float* __restrict__ invc,
                                                const float* __restrict__ lng,
                                                const float* __restrict__ lnb,
                                                uint32* __restrict__ OUTb, int n) {
  int lane = threadIdx.x & 63;
  int node = blockIdx.x * 4 + (threadIdx.x >> 6);
  if (node >= n) return;
  int beg = rowptr[node], end = rowptr[node + 1];
  float2 w = ((const float2*)ew)[lane];
  float2 b = ((const float2*)eb)[lane];
  float ax = 0.f, ay = 0.f;
  int i = beg;
  for (; i + 4 <= end; i += 4) {
    int s0 = csrc[i], s1 = csrc[i + 1], s2 = csrc[i + 2], s3 = csrc[i + 3];
    float a0 = cea[i], a1 = cea[i + 1], a2 = cea[i + 2], a3 = cea[i + 3];
    uint32 p0 = Hb[(size_t)s0 * 64 + lane];
    uint32 p1 = Hb[(size_t)s1 * 64 + lane];
    uint32 p2 = Hb[(size_t)s2 * 64 + lane];
    uint32 p3 = Hb[(size_t)s3 * 64 + lane];
    ax += bflo(p0) + fmaxf(a0 * w.x + b.x, 0.f) + bflo(p1) + fmaxf(a1 * w.x + b.x, 0.f) +
          bflo(p2) + fmaxf(a2 * w.x + b.x, 0.f) + bflo(p3) + fmaxf(a3 * w.x + b.x, 0.f);
    ay += bfhi(p0) + fmaxf(a0 * w.y + b.y, 0.f) + bfhi(p1) + fmaxf(a1 * w.y + b.y, 0.f) +
          bfhi(p2) + fmaxf(a2 * w.y + b.y, 0.f) + bfhi(p3) + fmaxf(a3 * w.y + b.y, 0.f);
  }
  for (; i < end; i++) {
    int s = csrc[i];
    float a = cea[i];
    uint32 p = Hb[(size_t)s * 64 + lane];
    ax += bflo(p) + fmaxf(a * w.x + b.x, 0.f);
    ay += bfhi(p) + fmaxf(a * w.y + b.y, 0.f);
  }
  float ic = invc[node];
  float ox = fmaxf(ax * ic, 0.f);
  float oy = fmaxf(ay * ic, 0.f);
  float s1 = ox + oy;
  float s2 = ox * ox + oy * oy;
  for (int off = 32; off; off >>= 1) {
    s1 += __shfl_xor(s1, off, 64);
    s2 += __shfl_xor(s2, off, 64);
  }
  float mu = s1 * (1.f / 128.f);
  float var = s2 * (1.f / 128.f) - mu * mu;
  float r = rsqrtf(var + LN_EPS);
  float2 g = ((const float2*)lng)[lane];
  float2 bb = ((const float2*)lnb)[lane];
  ox = (ox - mu) * r * g.x + bb.x;
  oy = (oy - mu) * r * g.y + bb.y;
  OUTb[(size_t)node * 64 + lane] = pack2(ox, oy);
}

// ---------------- fp32 layer-2 kernels (F=64, output precision) ----------------
__global__ __launch_bounds__(256) void k_agg64(const float* __restrict__ XW,
                                               const float* __restrict__ dis,
                                               const int* __restrict__ rowptr,
                                               const int* __restrict__ csrc,
                                               const float* __restrict__ bias,
                                               float* __restrict__ H, int n) {
  int lane = threadIdx.x & 63;
  int node = blockIdx.x * 4 + (threadIdx.x >> 6);
  if (node >= n) return;
  float dn = dis[node];
  int beg = rowptr[node], end = rowptr[node + 1];
  float acc = 0.f;
  int i = beg;
  for (; i + 4 <= end; i += 4) {
    int s0 = csrc[i], s1 = csrc[i + 1], s2 = csrc[i + 2], s3 = csrc[i + 3];
    float n0 = dn * dis[s0], n1 = dn * dis[s1], n2 = dn * dis[s2], n3 = dn * dis[s3];
    acc += n0 * XW[(size_t)s0 * 64 + lane] + n1 * XW[(size_t)s1 * 64 + lane] +
           n2 * XW[(size_t)s2 * 64 + lane] + n3 * XW[(size_t)s3 * 64 + lane];
  }
  for (; i < end; i++) {
    int s = csrc[i];
    acc += dn * dis[s] * XW[(size_t)s * 64 + lane];
  }
  float d2 = dn * dn;
  H[(size_t)node * 64 + lane] = acc + d2 * XW[(size_t)node * 64 + lane] + bias[lane];
}

__global__ __launch_bounds__(256) void k_msg64(const float* __restrict__ H,
                                               const float* __restrict__ ew,
                                               const float* __restrict__ eb,
                                               const int* __restrict__ rowptr,
                                               const int* __restrict__ csrc,
                                               const float* __restrict__ cea,
                                               const float* __restrict__ invc,
                                               float* __restrict__ OUT, int n) {
  int lane = threadIdx.x & 63;
  int node = blockIdx.x * 4 + (threadIdx.x >> 6);
  if (node >= n) return;
  int beg = rowptr[node], end = rowptr[node + 1];
  float w = ew[lane], b = eb[lane];
  float acc = 0.f;
  int i = beg;
  for (; i + 4 <= end; i += 4) {
    int s0 = csrc[i], s1 = csrc[i + 1], s2 = csrc[i + 2], s3 = csrc[i + 3];
    float a0 = cea[i], a1 = cea[i + 1], a2 = cea[i + 2], a3 = cea[i + 3];
    acc += H[(size_t)s0 * 64 + lane] + fmaxf(a0 * w + b, 0.f) +
           H[(size_t)s1 * 64 + lane] + fmaxf(a1 * w + b, 0.f) +
           H[(size_t)s2 * 64 + lane] + fmaxf(a2 * w + b, 0.f) +
           H[(size_t)s3 * 64 + lane] + fmaxf(a3 * w + b, 0.f);
  }
  for (; i < end; i++) {
    int s = csrc[i];
    acc += H[(size_t)s * 64 + lane] + fmaxf(cea[i] * w + b, 0.f);
  }
  OUT[(size_t)node * 64 + lane] = acc * invc[node];
}

// ------- global mean pool, phase 1: per-wave slice accumulate + atomic flush -------
// batch is sorted; each wave owns a contiguous node slice and flushes one
// atomicAdd per (graph-segment x lane). 1024 waves -> ~49 nodes each.
#define POOL_BLOCKS 256
__global__ __launch_bounds__(256) void k_pool_partial(const float* __restrict__ H,
                                                      const int* __restrict__ batch,
                                                      float* __restrict__ Z, int n) {
  int lane = threadIdx.x & 63;
  int wid = blockIdx.x * 4 + (threadIdx.x >> 6);
  const int WAVES = POOL_BLOCKS * 4;
  int per = (n + WAVES - 1) / WAVES;
  int beg = wid * per;
  int end = beg + per;
  if (end > n) end = n;
  if (beg >= end) return;
  int g = batch[beg];
  float acc = 0.f;
  for (int i = beg; i < end; i++) {
    int gi = batch[i];
    if (gi != g) {
      atomicAdd(&Z[g * 64 + lane], acc);
      acc = 0.f;
      g = gi;
    }
    acc += H[(size_t)i * 64 + lane];
  }
  atomicAdd(&Z[g * 64 + lane], acc);
}

// ------- global mean pool, phase 2: divide by per-graph count -------
__global__ __launch_bounds__(64) void k_pool_div(float* __restrict__ Z,
                                                 const int* __restrict__ batch, int n) {
  int g = blockIdx.x;
  __shared__ int scnt;
  if (threadIdx.x == 0) {
    int lo = 0, hi = n;
    while (lo < hi) { int m = (lo + hi) >> 1; if (batch[m] < g) lo = m + 1; else hi = m; }
    int b0 = lo;
    lo = 0; hi = n;
    while (lo < hi) { int m = (lo + hi) >> 1; if (batch[m] < g + 1) lo = m + 1; else hi = m; }
    scnt = lo - b0;
  }
  __syncthreads();
  float c = (float)scnt;
  if (c < 1.f) c = 1.f;
  Z[g * 64 + threadIdx.x] /= c;
}

extern "C" void kernel_launch(void* const* d_in, const int* in_sizes, int n_in,
                              void* d_out, int out_size, void* d_ws, size_t ws_size,
                              hipStream_t stream) {
  const float* x = (const float*)d_in[0];
  const int* ei = (const int*)d_in[1];
  const float* ea = (const float*)d_in[2];
  const int* batch = (const int*)d_in[3];
  const float* gw0 = (const float*)d_in[4];
  const float* gb0 = (const float*)d_in[5];
  const float* ew0 = (const float*)d_in[6];
  const float* eb0 = (const float*)d_in[7];
  const float* lg0 = (const float*)d_in[8];
  const float* lb0 = (const float*)d_in[9];
  const float* gw1 = (const float*)d_in[10];
  const float* gb1 = (const float*)d_in[11];
  const float* ew1 = (const float*)d_in[12];
  const float* eb1 = (const float*)d_in[13];
  const float* lg1 = (const float*)d_in[14];
  const float* lb1 = (const float*)d_in[15];
  const float* gw2 = (const float*)d_in[16];
  const float* gb2 = (const float*)d_in[17];
  const float* ew2 = (const float*)d_in[18];
  const float* eb2 = (const float*)d_in[19];
  float* out = (float*)d_out;

  const int* src = ei;
  const int* dst = ei + NE;

  char* w = (char*)d_ws;
  size_t off = 0;
  auto alloc = [&](size_t bytes) -> void* {
    void* p = (void*)(w + off);
    off = (off + bytes + 255) & ~(size_t)255;
    return p;
  };
  int* deg = (int*)alloc(NN * sizeof(int));
  int* rowptr = (int*)alloc((NN + 1) * sizeof(int));
  int* blocksum = (int*)alloc(128 * sizeof(int));
  int* cursor = (int*)alloc(NN * sizeof(int));
  int* csrc = (int*)alloc(NE * sizeof(int));
  float* cea = (float*)alloc(NE * sizeof(float));
  float* dis = (float*)alloc(NN * sizeof(float));
  float* invc = (float*)alloc(NN * sizeof(float));
  uint32* B1b = (uint32*)alloc((size_t)NN * 64 * sizeof(uint32));  // 128 bf16/row
  uint32* B2b = (uint32*)alloc((size_t)NN * 64 * sizeof(uint32));
  float* F1 = (float*)alloc((size_t)NN * 64 * sizeof(float));
  float* F2 = (float*)alloc((size_t)NN * 64 * sizeof(float));

  const int nb_scan = (NN + SCAN_T - 1) / SCAN_T;  // 98

  hipLaunchKernelGGL(k_zero_int, dim3((NN + 255) / 256), dim3(256), 0, stream, deg, NN);
  hipLaunchKernelGGL(k_deg, dim3((NE + 255) / 256), dim3(256), 0, stream, dst, deg, NE);
  hipLaunchKernelGGL(k_scan_a, dim3(nb_scan), dim3(SCAN_T), 0, stream, deg, rowptr, blocksum, NN);
  hipLaunchKernelGGL(k_scan_b, dim3(1), dim3(128), 0, stream, blocksum, nb_scan);
  hipLaunchKernelGGL(k_scan_c, dim3(nb_scan), dim3(SCAN_T), 0, stream, deg, rowptr, blocksum,
                     cursor, dis, invc, NN, NE);
  hipLaunchKernelGGL(k_fill, dim3((NE + 255) / 256), dim3(256), 0, stream, src, dst, ea, cursor,
                     csrc, cea, NE);

  dim3 gemm_grid((NN + 31) / 32), tb(256);
  dim3 node_grid((NN + 3) / 4);

  // Layer 0: x(fp32) -> B1b(xw bf16) -> B2b(h bf16) -> B1b(relu+LN bf16)
  hipLaunchKernelGGL((k_gemm<128, false, true>), gemm_grid, tb, 0, stream, x, gw0, B1b, NN);
  hipLaunchKernelGGL(k_agg_bf, node_grid, tb, 0, stream, B1b, dis, rowptr, csrc, gb0, B2b, NN);
  hipLaunchKernelGGL(k_msg_bf, node_grid, tb, 0, stream, B2b, ew0, eb0, rowptr, csrc, cea, invc,
                     lg0, lb0, B1b, NN);
  // Layer 1: B1b -> B2b(xw) -> B1b(h) -> B2b(relu+LN)
  hipLaunchKernelGGL((k_gemm<128, true, true>), gemm_grid, tb, 0, stream, B1b, gw1, B2b, NN);
  hipLaunchKernelGGL(k_agg_bf, node_grid, tb, 0, stream, B2b, dis, rowptr, csrc, gb1, B1b, NN);
  hipLaunchKernelGGL(k_msg_bf, node_grid, tb, 0, stream, B1b, ew1, eb1, rowptr, csrc, cea, invc,
                     lg1, lb1, B2b, NN);
  // Layer 2 (fp32): B2b -> F1(xw) -> F2(h) -> d_out
  hipLaunchKernelGGL((k_gemm<64, true, false>), gemm_grid, tb, 0, stream, B2b, gw2, F1, NN);
  hipLaunchKernelGGL(k_agg64, node_grid, tb, 0, stream, F1, dis, rowptr, csrc, gb2, F2, NN);
  hipLaunchKernelGGL(k_msg64, node_grid, tb, 0, stream, F2, ew2, eb2, rowptr, csrc, cea, invc,
                     out, NN);
  // Pool: zero accumulators, per-slice partial sums, divide by counts
  float* Z = out + (size_t)NN * 64;
  hipLaunchKernelGGL(k_zero_f, dim3((NG * 64 + 255) / 256), dim3(256), 0, stream, Z, NG * 64);
  hipLaunchKernelGGL(k_pool_partial, dim3(POOL_BLOCKS), tb, 0, stream, out, batch, Z, NN);
  hipLaunchKernelGGL(k_pool_div, dim3(NG), dim3(64), 0, stream, Z, batch, NN);
}

// Round 5
// 508.950 us; speedup vs baseline: 3.5958x; 1.1213x over previous
//
#include <hip/hip_runtime.h>

#define NN 50000
#define NE 800000
#define NG 64
#define HID 128
#define DOUT 64
#define LN_EPS 1e-5f
#define NBUK 391   // ceil(50000/128) coarse buckets of 128 dst nodes
#define BCAP 3072  // capacity per bucket (mean 2048, sigma ~45 -> 22 sigma)
#define EPB 8192   // edges per k_bucket block

typedef unsigned int uint32;
typedef unsigned short ushort16;

// ---- bf16 helpers (RNE pack, cheap unpack) ----
__device__ inline ushort16 f2bf(float f) {
  uint32 u = __float_as_uint(f);
  u += 0x7fffu + ((u >> 16) & 1u);
  return (ushort16)(u >> 16);
}
__device__ inline uint32 pack2(float x, float y) {
  return (uint32)f2bf(x) | ((uint32)f2bf(y) << 16);
}
__device__ inline float bflo(uint32 p) { return __uint_as_float(p << 16); }
__device__ inline float bfhi(uint32 p) { return __uint_as_float(p & 0xffff0000u); }

__global__ __launch_bounds__(256) void k_zero_f(float* p, int n) {
  int i = blockIdx.x * 256 + threadIdx.x;
  if (i < n) p[i] = 0.f;
}

// ---------------- CSR build: bucket counting sort ----------------
__global__ __launch_bounds__(256) void k_init_bcur(int* __restrict__ bcur) {
  int i = blockIdx.x * 256 + threadIdx.x;
  if (i < NBUK) bcur[i] = i * BCAP;
}

// Phase 1: LDS-histogram per block, one global reservation per (block,bucket),
// write packed 8B records (src:16 | dstoff:7, ea) grouped by bucket.
__global__ __launch_bounds__(1024) void k_bucket(const int* __restrict__ src,
                                                 const int* __restrict__ dst,
                                                 const float* __restrict__ ea,
                                                 int* __restrict__ bcur,
                                                 uint2* __restrict__ tmp, int e) {
  __shared__ int hist[NBUK], lbase[NBUK], lcur[NBUK];
  int t = threadIdx.x;
  for (int i = t; i < NBUK; i += 1024) {
    hist[i] = 0;
    lcur[i] = 0;
  }
  __syncthreads();
  int base_e = blockIdx.x * EPB;
  int dstv[EPB / 1024];
#pragma unroll
  for (int k = 0; k < EPB / 1024; k++) {
    int i = base_e + k * 1024 + t;
    int d = (i < e) ? dst[i] : -1;
    dstv[k] = d;
    if (d >= 0) atomicAdd(&hist[d >> 7], 1);
  }
  __syncthreads();
  for (int i = t; i < NBUK; i += 1024) {
    int c = hist[i];
    int b = 0;
    if (c > 0) b = atomicAdd(&bcur[i], c);
    lbase[i] = b;
  }
  __syncthreads();
#pragma unroll
  for (int k = 0; k < EPB / 1024; k++) {
    int i = base_e + k * 1024 + t;
    int d = dstv[k];
    if (d >= 0) {
      int b = d >> 7;
      int r = atomicAdd(&lcur[b], 1);
      int pos = lbase[b] + r;
      if (pos < (b + 1) * BCAP) {  // capacity guard (never hit for this data)
        uint2 rec;
        rec.x = (uint32)(src[i] & 0xffff) | ((uint32)(d & 127) << 16);
        rec.y = __float_as_uint(ea[i]);
        tmp[pos] = rec;
      }
    }
  }
}

// Phase 2: exclusive scan of bucket counts -> bucket bases; rowptr[NN]=NE.
__global__ __launch_bounds__(512) void k_bscan(const int* __restrict__ bcur,
                                               int* __restrict__ bbase,
                                               int* __restrict__ rowptr) {
  __shared__ int s[512];
  int t = threadIdx.x;
  int v = 0;
  if (t < NBUK) {
    v = bcur[t] - t * BCAP;
    if (v > BCAP) v = BCAP;
  }
  s[t] = v;
  __syncthreads();
  for (int off = 1; off < 512; off <<= 1) {
    int x = (t >= off) ? s[t - off] : 0;
    __syncthreads();
    s[t] += x;
    __syncthreads();
  }
  if (t < NBUK) bbase[t] = s[t] - v;
  if (t == 511) {
    bbase[NBUK] = s[511];
    rowptr[NN] = s[511];
  }
}

// Phase 3: one block per bucket (exclusive ownership of its output region ->
// full-line evictions). LDS histogram of 128 nodes, scan, emit final CSR +
// rowptr + dis + invc.
__global__ __launch_bounds__(256) void k_bsort(const uint2* __restrict__ tmp,
                                               const int* __restrict__ bcur,
                                               const int* __restrict__ bbase,
                                               int* __restrict__ rowptr,
                                               int* __restrict__ csrc,
                                               float* __restrict__ cea,
                                               float* __restrict__ dis,
                                               float* __restrict__ invc) {
  int b = blockIdx.x;
  __shared__ int hist[128], excl[128], cur[128];
  int t = threadIdx.x;
  if (t < 128) {
    hist[t] = 0;
    cur[t] = 0;
  }
  __syncthreads();
  int cnt = bcur[b] - b * BCAP;
  if (cnt > BCAP) cnt = BCAP;
  int tb = b * BCAP;
  int ob = bbase[b];
  for (int i = t; i < cnt; i += 256) {
    uint2 r = tmp[tb + i];
    atomicAdd(&hist[(r.x >> 16) & 127], 1);
  }
  __syncthreads();
  int myDeg = (t < 128) ? hist[t] : 0;
  for (int off = 1; off < 128; off <<= 1) {
    int x = 0;
    if (t < 128 && t >= off) x = hist[t - off];
    __syncthreads();
    if (t < 128) hist[t] += x;
    __syncthreads();
  }
  if (t < 128) {
    excl[t] = hist[t] - myDeg;  // exclusive scan within bucket
    int node = (b << 7) + t;
    if (node < NN) {
      rowptr[node] = ob + excl[t];
      dis[node] = rsqrtf((float)(myDeg + 1));
      invc[node] = (myDeg > 0) ? 1.0f / (float)myDeg : 1.0f;
    }
  }
  __syncthreads();
  for (int i = t; i < cnt; i += 256) {
    uint2 r = tmp[tb + i];
    int o = (r.x >> 16) & 127;
    int p = atomicAdd(&cur[o], 1);
    int pos = ob + excl[o] + p;
    csrc[pos] = (int)(r.x & 0xffffu);
    cea[pos] = __uint_as_float(r.y);
  }
}

// ---------------- GEMM: Y[n,FOUT] = X[n,128] @ W[128,FOUT] ----------------
// 32 rows/block, thread tile = RPT rows x 4 cols, bounded k-unroll (VGPR-safe).
template <int FOUT, bool IN_BF, bool OUT_BF>
__global__ __launch_bounds__(256) void k_gemm(const void* __restrict__ Xv,
                                              const float* __restrict__ W,
                                              void* __restrict__ Yv, int n) {
  const int FI = 128;
  __shared__ __align__(16) float xs[32][FI];
  int t = threadIdx.x;
  int row0 = blockIdx.x * 32;
  if (IN_BF) {
    const ushort16* Xb = (const ushort16*)Xv;
    for (int i = t; i < 32 * 32; i += 256) {
      int r = i >> 5, c = i & 31;
      uint2 v = make_uint2(0u, 0u);
      if (row0 + r < n) v = ((const uint2*)(Xb + (size_t)(row0 + r) * FI))[c];
      float4 f = {bflo(v.x), bfhi(v.x), bflo(v.y), bfhi(v.y)};
      ((float4*)xs[r])[c] = f;
    }
  } else {
    const float* X = (const float*)Xv;
    for (int i = t; i < 32 * FI / 4; i += 256) {
      int r = i / (FI / 4);
      int c = i % (FI / 4);
      float4 v = make_float4(0.f, 0.f, 0.f, 0.f);
      if (row0 + r < n) v = ((const float4*)(X + (size_t)(row0 + r) * FI))[c];
      ((float4*)xs[r])[c] = v;
    }
  }
  __syncthreads();
  const int CG = FOUT / 4;
  const int RG = 256 / CG;
  const int RPT = 32 / RG;
  int cg = t % CG;
  int rg = t / CG;
  float acc[RPT][4];
#pragma unroll
  for (int r = 0; r < RPT; r++)
#pragma unroll
    for (int c = 0; c < 4; c++) acc[r][c] = 0.f;

#pragma unroll 2
  for (int k4 = 0; k4 < FI / 4; k4++) {
    float4 wv[4];
#pragma unroll
    for (int kk = 0; kk < 4; kk++)
      wv[kk] = ((const float4*)(W + (size_t)(4 * k4 + kk) * FOUT))[cg];
#pragma unroll
    for (int r = 0; r < RPT; r++) {
      float4 xv = ((const float4*)xs[rg * RPT + r])[k4];
      acc[r][0] += xv.x * wv[0].x + xv.y * wv[1].x + xv.z * wv[2].x + xv.w * wv[3].x;
      acc[r][1] += xv.x * wv[0].y + xv.y * wv[1].y + xv.z * wv[2].y + xv.w * wv[3].y;
      acc[r][2] += xv.x * wv[0].z + xv.y * wv[1].z + xv.z * wv[2].z + xv.w * wv[3].z;
      acc[r][3] += xv.x * wv[0].w + xv.y * wv[1].w + xv.z * wv[2].w + xv.w * wv[3].w;
    }
  }
#pragma unroll
  for (int r = 0; r < RPT; r++) {
    int row = row0 + rg * RPT + r;
    if (row < n) {
      if (OUT_BF) {
        uint2 o = {pack2(acc[r][0], acc[r][1]), pack2(acc[r][2], acc[r][3])};
        ((uint2*)((ushort16*)Yv + (size_t)row * FOUT))[cg] = o;
      } else {
        float4 o = {acc[r][0], acc[r][1], acc[r][2], acc[r][3]};
        ((float4*)((float*)Yv + (size_t)row * FOUT))[cg] = o;
      }
    }
  }
}

// ------- GCN aggregation, bf16 tables (F=128): H = agg + dis^2*XW + b -------
__global__ __launch_bounds__(256) void k_agg_bf(const uint32* __restrict__ XWb,
                                                const float* __restrict__ dis,
                                                const int* __restrict__ rowptr,
                                                const int* __restrict__ csrc,
                                                const float* __restrict__ bias,
                                                uint32* __restrict__ Hb, int n) {
  int lane = threadIdx.x & 63;
  int node = blockIdx.x * 4 + (threadIdx.x >> 6);
  if (node >= n) return;
  float dn = dis[node];
  int beg = rowptr[node], end = rowptr[node + 1];
  float ax = 0.f, ay = 0.f;
  int i = beg;
  for (; i + 4 <= end; i += 4) {
    int s0 = csrc[i], s1 = csrc[i + 1], s2 = csrc[i + 2], s3 = csrc[i + 3];
    float n0 = dn * dis[s0], n1 = dn * dis[s1], n2 = dn * dis[s2], n3 = dn * dis[s3];
    uint32 p0 = XWb[(size_t)s0 * 64 + lane];
    uint32 p1 = XWb[(size_t)s1 * 64 + lane];
    uint32 p2 = XWb[(size_t)s2 * 64 + lane];
    uint32 p3 = XWb[(size_t)s3 * 64 + lane];
    ax += n0 * bflo(p0) + n1 * bflo(p1) + n2 * bflo(p2) + n3 * bflo(p3);
    ay += n0 * bfhi(p0) + n1 * bfhi(p1) + n2 * bfhi(p2) + n3 * bfhi(p3);
  }
  for (; i < end; i++) {
    int s = csrc[i];
    float nr = dn * dis[s];
    uint32 p = XWb[(size_t)s * 64 + lane];
    ax += nr * bflo(p);
    ay += nr * bfhi(p);
  }
  uint32 ps = XWb[(size_t)node * 64 + lane];
  float2 bb = ((const float2*)bias)[lane];
  float d2 = dn * dn;
  float hx = ax + d2 * bflo(ps) + bb.x;
  float hy = ay + d2 * bfhi(ps) + bb.y;
  Hb[(size_t)node * 64 + lane] = pack2(hx, hy);
}

// -- mean-agg of h[src]+relu(ea*ew+eb), ReLU+LN epilogue, bf16 tables (F=128) --
__global__ __launch_bounds__(256) void k_msg_bf(const uint32* __restrict__ Hb,
                                                const float* __restrict__ ew,
                                                const float* __restrict__ eb,
                                                const int* __restrict__ rowptr,
                                                const int* __restrict__ csrc,
                                                const float* __restrict__ cea,
                                                const float* __restrict__ invc,
                                                const float* __restrict__ lng,
                                                const float* __restrict__ lnb,
                                                uint32* __restrict__ OUTb, int n) {
  int lane = threadIdx.x & 63;
  int node = blockIdx.x * 4 + (threadIdx.x >> 6);
  if (node >= n) return;
  int beg = rowptr[node], end = rowptr[node + 1];
  float2 w = ((const float2*)ew)[lane];
  float2 b = ((const float2*)eb)[lane];
  float ax = 0.f, ay = 0.f;
  int i = beg;
  for (; i + 4 <= end; i += 4) {
    int s0 = csrc[i], s1 = csrc[i + 1], s2 = csrc[i + 2], s3 = csrc[i + 3];
    float a0 = cea[i], a1 = cea[i + 1], a2 = cea[i + 2], a3 = cea[i + 3];
    uint32 p0 = Hb[(size_t)s0 * 64 + lane];
    uint32 p1 = Hb[(size_t)s1 * 64 + lane];
    uint32 p2 = Hb[(size_t)s2 * 64 + lane];
    uint32 p3 = Hb[(size_t)s3 * 64 + lane];
    ax += bflo(p0) + fmaxf(a0 * w.x + b.x, 0.f) + bflo(p1) + fmaxf(a1 * w.x + b.x, 0.f) +
          bflo(p2) + fmaxf(a2 * w.x + b.x, 0.f) + bflo(p3) + fmaxf(a3 * w.x + b.x, 0.f);
    ay += bfhi(p0) + fmaxf(a0 * w.y + b.y, 0.f) + bfhi(p1) + fmaxf(a1 * w.y + b.y, 0.f) +
          bfhi(p2) + fmaxf(a2 * w.y + b.y, 0.f) + bfhi(p3) + fmaxf(a3 * w.y + b.y, 0.f);
  }
  for (; i < end; i++) {
    int s = csrc[i];
    float a = cea[i];
    uint32 p = Hb[(size_t)s * 64 + lane];
    ax += bflo(p) + fmaxf(a * w.x + b.x, 0.f);
    ay += bfhi(p) + fmaxf(a * w.y + b.y, 0.f);
  }
  float ic = invc[node];
  float ox = fmaxf(ax * ic, 0.f);
  float oy = fmaxf(ay * ic, 0.f);
  float s1 = ox + oy;
  float s2 = ox * ox + oy * oy;
  for (int off = 32; off; off >>= 1) {
    s1 += __shfl_xor(s1, off, 64);
    s2 += __shfl_xor(s2, off, 64);
  }
  float mu = s1 * (1.f / 128.f);
  float var = s2 * (1.f / 128.f) - mu * mu;
  float r = rsqrtf(var + LN_EPS);
  float2 g = ((const float2*)lng)[lane];
  float2 bb = ((const float2*)lnb)[lane];
  ox = (ox - mu) * r * g.x + bb.x;
  oy = (oy - mu) * r * g.y + bb.y;
  OUTb[(size_t)node * 64 + lane] = pack2(ox, oy);
}

// ---------------- fp32 layer-2 kernels (F=64, output precision) ----------------
__global__ __launch_bounds__(256) void k_agg64(const float* __restrict__ XW,
                                               const float* __restrict__ dis,
                                               const int* __restrict__ rowptr,
                                               const int* __restrict__ csrc,
                                               const float* __restrict__ bias,
                                               float* __restrict__ H, int n) {
  int lane = threadIdx.x & 63;
  int node = blockIdx.x * 4 + (threadIdx.x >> 6);
  if (node >= n) return;
  float dn = dis[node];
  int beg = rowptr[node], end = rowptr[node + 1];
  float acc = 0.f;
  int i = beg;
  for (; i + 4 <= end; i += 4) {
    int s0 = csrc[i], s1 = csrc[i + 1], s2 = csrc[i + 2], s3 = csrc[i + 3];
    float n0 = dn * dis[s0], n1 = dn * dis[s1], n2 = dn * dis[s2], n3 = dn * dis[s3];
    acc += n0 * XW[(size_t)s0 * 64 + lane] + n1 * XW[(size_t)s1 * 64 + lane] +
           n2 * XW[(size_t)s2 * 64 + lane] + n3 * XW[(size_t)s3 * 64 + lane];
  }
  for (; i < end; i++) {
    int s = csrc[i];
    acc += dn * dis[s] * XW[(size_t)s * 64 + lane];
  }
  float d2 = dn * dn;
  H[(size_t)node * 64 + lane] = acc + d2 * XW[(size_t)node * 64 + lane] + bias[lane];
}

__global__ __launch_bounds__(256) void k_msg64(const float* __restrict__ H,
                                               const float* __restrict__ ew,
                                               const float* __restrict__ eb,
                                               const int* __restrict__ rowptr,
                                               const int* __restrict__ csrc,
                                               const float* __restrict__ cea,
                                               const float* __restrict__ invc,
                                               float* __restrict__ OUT, int n) {
  int lane = threadIdx.x & 63;
  int node = blockIdx.x * 4 + (threadIdx.x >> 6);
  if (node >= n) return;
  int beg = rowptr[node], end = rowptr[node + 1];
  float w = ew[lane], b = eb[lane];
  float acc = 0.f;
  int i = beg;
  for (; i + 4 <= end; i += 4) {
    int s0 = csrc[i], s1 = csrc[i + 1], s2 = csrc[i + 2], s3 = csrc[i + 3];
    float a0 = cea[i], a1 = cea[i + 1], a2 = cea[i + 2], a3 = cea[i + 3];
    acc += H[(size_t)s0 * 64 + lane] + fmaxf(a0 * w + b, 0.f) +
           H[(size_t)s1 * 64 + lane] + fmaxf(a1 * w + b, 0.f) +
           H[(size_t)s2 * 64 + lane] + fmaxf(a2 * w + b, 0.f) +
           H[(size_t)s3 * 64 + lane] + fmaxf(a3 * w + b, 0.f);
  }
  for (; i < end; i++) {
    int s = csrc[i];
    acc += H[(size_t)s * 64 + lane] + fmaxf(cea[i] * w + b, 0.f);
  }
  OUT[(size_t)node * 64 + lane] = acc * invc[node];
}

// ------- global mean pool, phase 1: per-wave slice accumulate + atomic flush -------
#define POOL_BLOCKS 256
__global__ __launch_bounds__(256) void k_pool_partial(const float* __restrict__ H,
                                                      const int* __restrict__ batch,
                                                      float* __restrict__ Z, int n) {
  int lane = threadIdx.x & 63;
  int wid = blockIdx.x * 4 + (threadIdx.x >> 6);
  const int WAVES = POOL_BLOCKS * 4;
  int per = (n + WAVES - 1) / WAVES;
  int beg = wid * per;
  int end = beg + per;
  if (end > n) end = n;
  if (beg >= end) return;
  int g = batch[beg];
  float acc = 0.f;
  for (int i = beg; i < end; i++) {
    int gi = batch[i];
    if (gi != g) {
      atomicAdd(&Z[g * 64 + lane], acc);
      acc = 0.f;
      g = gi;
    }
    acc += H[(size_t)i * 64 + lane];
  }
  atomicAdd(&Z[g * 64 + lane], acc);
}

// ------- global mean pool, phase 2: divide by per-graph count -------
__global__ __launch_bounds__(64) void k_pool_div(float* __restrict__ Z,
                                                 const int* __restrict__ batch, int n) {
  int g = blockIdx.x;
  __shared__ int scnt;
  if (threadIdx.x == 0) {
    int lo = 0, hi = n;
    while (lo < hi) { int m = (lo + hi) >> 1; if (batch[m] < g) lo = m + 1; else hi = m; }
    int b0 = lo;
    lo = 0; hi = n;
    while (lo < hi) { int m = (lo + hi) >> 1; if (batch[m] < g + 1) lo = m + 1; else hi = m; }
    scnt = lo - b0;
  }
  __syncthreads();
  float c = (float)scnt;
  if (c < 1.f) c = 1.f;
  Z[g * 64 + threadIdx.x] /= c;
}

extern "C" void kernel_launch(void* const* d_in, const int* in_sizes, int n_in,
                              void* d_out, int out_size, void* d_ws, size_t ws_size,
                              hipStream_t stream) {
  const float* x = (const float*)d_in[0];
  const int* ei = (const int*)d_in[1];
  const float* ea = (const float*)d_in[2];
  const int* batch = (const int*)d_in[3];
  const float* gw0 = (const float*)d_in[4];
  const float* gb0 = (const float*)d_in[5];
  const float* ew0 = (const float*)d_in[6];
  const float* eb0 = (const float*)d_in[7];
  const float* lg0 = (const float*)d_in[8];
  const float* lb0 = (const float*)d_in[9];
  const float* gw1 = (const float*)d_in[10];
  const float* gb1 = (const float*)d_in[11];
  const float* ew1 = (const float*)d_in[12];
  const float* eb1 = (const float*)d_in[13];
  const float* lg1 = (const float*)d_in[14];
  const float* lb1 = (const float*)d_in[15];
  const float* gw2 = (const float*)d_in[16];
  const float* gb2 = (const float*)d_in[17];
  const float* ew2 = (const float*)d_in[18];
  const float* eb2 = (const float*)d_in[19];
  float* out = (float*)d_out;

  const int* src = ei;
  const int* dst = ei + NE;

  char* w = (char*)d_ws;
  size_t off = 0;
  auto alloc = [&](size_t bytes) -> void* {
    void* p = (void*)(w + off);
    off = (off + bytes + 255) & ~(size_t)255;
    return p;
  };
  int* rowptr = (int*)alloc((NN + 1) * sizeof(int));
  int* bcur = (int*)alloc(NBUK * sizeof(int));
  int* bbase = (int*)alloc((NBUK + 1) * sizeof(int));
  int* csrc = (int*)alloc(NE * sizeof(int));
  float* cea = (float*)alloc(NE * sizeof(float));
  float* dis = (float*)alloc(NN * sizeof(float));
  float* invc = (float*)alloc(NN * sizeof(float));
  uint32* B1b = (uint32*)alloc((size_t)NN * 64 * sizeof(uint32));  // 128 bf16/row
  uint32* B2b = (uint32*)alloc((size_t)NN * 64 * sizeof(uint32));
  float* F1 = (float*)alloc((size_t)NN * 64 * sizeof(float));  // 12.8 MB
  float* F2 = (float*)alloc((size_t)NN * 64 * sizeof(float));
  uint2* tmp = (uint2*)F1;  // 9.6 MB needed; F1 dead until layer-2 GEMM

  // ---- CSR build (bucket counting sort; no 800K-wide global atomics) ----
  hipLaunchKernelGGL(k_init_bcur, dim3((NBUK + 255) / 256), dim3(256), 0, stream, bcur);
  hipLaunchKernelGGL(k_bucket, dim3((NE + EPB - 1) / EPB), dim3(1024), 0, stream, src, dst, ea,
                     bcur, tmp, NE);
  hipLaunchKernelGGL(k_bscan, dim3(1), dim3(512), 0, stream, bcur, bbase, rowptr);
  hipLaunchKernelGGL(k_bsort, dim3(NBUK), dim3(256), 0, stream, tmp, bcur, bbase, rowptr, csrc,
                     cea, dis, invc);

  dim3 gemm_grid((NN + 31) / 32), tb(256);
  dim3 node_grid((NN + 3) / 4);

  // Layer 0: x(fp32) -> B1b(xw bf16) -> B2b(h bf16) -> B1b(relu+LN bf16)
  hipLaunchKernelGGL((k_gemm<128, false, true>), gemm_grid, tb, 0, stream, x, gw0, B1b, NN);
  hipLaunchKernelGGL(k_agg_bf, node_grid, tb, 0, stream, B1b, dis, rowptr, csrc, gb0, B2b, NN);
  hipLaunchKernelGGL(k_msg_bf, node_grid, tb, 0, stream, B2b, ew0, eb0, rowptr, csrc, cea, invc,
                     lg0, lb0, B1b, NN);
  // Layer 1: B1b -> B2b(xw) -> B1b(h) -> B2b(relu+LN)
  hipLaunchKernelGGL((k_gemm<128, true, true>), gemm_grid, tb, 0, stream, B1b, gw1, B2b, NN);
  hipLaunchKernelGGL(k_agg_bf, node_grid, tb, 0, stream, B2b, dis, rowptr, csrc, gb1, B1b, NN);
  hipLaunchKernelGGL(k_msg_bf, node_grid, tb, 0, stream, B1b, ew1, eb1, rowptr, csrc, cea, invc,
                     lg1, lb1, B2b, NN);
  // Layer 2 (fp32): B2b -> F1(xw) -> F2(h) -> d_out   (tmp is dead by now)
  hipLaunchKernelGGL((k_gemm<64, true, false>), gemm_grid, tb, 0, stream, B2b, gw2, F1, NN);
  hipLaunchKernelGGL(k_agg64, node_grid, tb, 0, stream, F1, dis, rowptr, csrc, gb2, F2, NN);
  hipLaunchKernelGGL(k_msg64, node_grid, tb, 0, stream, F2, ew2, eb2, rowptr, csrc, cea, invc,
                     out, NN);
  // Pool: zero accumulators, per-slice partial sums, divide by counts
  float* Z = out + (size_t)NN * 64;
  hipLaunchKernelGGL(k_zero_f, dim3((NG * 64 + 255) / 256), dim3(256), 0, stream, Z, NG * 64);
  hipLaunchKernelGGL(k_pool_partial, dim3(POOL_BLOCKS), tb, 0, stream, out, batch, Z, NN);
  hipLaunchKernelGGL(k_pool_div, dim3(NG), dim3(64), 0, stream, Z, batch, NN);
}

// Round 6
// 462.099 us; speedup vs baseline: 3.9604x; 1.1014x over previous
//
#include <hip/hip_runtime.h>

#define NN 50000
#define NE 800000
#define NG 64
#define HID 128
#define DOUT 64
#define LN_EPS 1e-5f
#define NBUK 391   // ceil(50000/128) coarse buckets of 128 dst nodes
#define BCAP 3072  // capacity per bucket
#define EPB 8192   // edges per k_bucket block

typedef unsigned int uint32;
typedef unsigned short ushort16;
typedef __attribute__((ext_vector_type(8))) short bf16x8;
typedef __attribute__((ext_vector_type(4))) float f32x4;

// ---- bf16 helpers (RNE pack, cheap unpack) ----
__device__ inline ushort16 f2bf(float f) {
  uint32 u = __float_as_uint(f);
  u += 0x7fffu + ((u >> 16) & 1u);
  return (ushort16)(u >> 16);
}
__device__ inline uint32 pack2(float x, float y) {
  return (uint32)f2bf(x) | ((uint32)f2bf(y) << 16);
}
__device__ inline float bflo(uint32 p) { return __uint_as_float(p << 16); }
__device__ inline float bfhi(uint32 p) { return __uint_as_float(p & 0xffff0000u); }

__global__ __launch_bounds__(256) void k_zero_f(float* p, int n) {
  int i = blockIdx.x * 256 + threadIdx.x;
  if (i < n) p[i] = 0.f;
}

// ---------------- CSR build: bucket counting sort ----------------
__global__ __launch_bounds__(256) void k_init_bcur(int* __restrict__ bcur) {
  int i = blockIdx.x * 256 + threadIdx.x;
  if (i < NBUK) bcur[i] = i * BCAP;
}

__global__ __launch_bounds__(1024) void k_bucket(const int* __restrict__ src,
                                                 const int* __restrict__ dst,
                                                 const float* __restrict__ ea,
                                                 int* __restrict__ bcur,
                                                 uint2* __restrict__ tmp, int e) {
  __shared__ int hist[NBUK], lbase[NBUK], lcur[NBUK];
  int t = threadIdx.x;
  for (int i = t; i < NBUK; i += 1024) {
    hist[i] = 0;
    lcur[i] = 0;
  }
  __syncthreads();
  int base_e = blockIdx.x * EPB;
  int dstv[EPB / 1024];
#pragma unroll
  for (int k = 0; k < EPB / 1024; k++) {
    int i = base_e + k * 1024 + t;
    int d = (i < e) ? dst[i] : -1;
    dstv[k] = d;
    if (d >= 0) atomicAdd(&hist[d >> 7], 1);
  }
  __syncthreads();
  for (int i = t; i < NBUK; i += 1024) {
    int c = hist[i];
    int b = 0;
    if (c > 0) b = atomicAdd(&bcur[i], c);
    lbase[i] = b;
  }
  __syncthreads();
#pragma unroll
  for (int k = 0; k < EPB / 1024; k++) {
    int i = base_e + k * 1024 + t;
    int d = dstv[k];
    if (d >= 0) {
      int b = d >> 7;
      int r = atomicAdd(&lcur[b], 1);
      int pos = lbase[b] + r;
      if (pos < (b + 1) * BCAP) {
        uint2 rec;
        rec.x = (uint32)(src[i] & 0xffff) | ((uint32)(d & 127) << 16);
        rec.y = __float_as_uint(ea[i]);
        tmp[pos] = rec;
      }
    }
  }
}

__global__ __launch_bounds__(512) void k_bscan(const int* __restrict__ bcur,
                                               int* __restrict__ bbase,
                                               int* __restrict__ rowptr) {
  __shared__ int s[512];
  int t = threadIdx.x;
  int v = 0;
  if (t < NBUK) {
    v = bcur[t] - t * BCAP;
    if (v > BCAP) v = BCAP;
  }
  s[t] = v;
  __syncthreads();
  for (int off = 1; off < 512; off <<= 1) {
    int x = (t >= off) ? s[t - off] : 0;
    __syncthreads();
    s[t] += x;
    __syncthreads();
  }
  if (t < NBUK) bbase[t] = s[t] - v;
  if (t == 511) {
    bbase[NBUK] = s[511];
    rowptr[NN] = s[511];
  }
}

__global__ __launch_bounds__(256) void k_bsort(const uint2* __restrict__ tmp,
                                               const int* __restrict__ bcur,
                                               const int* __restrict__ bbase,
                                               int* __restrict__ rowptr,
                                               int* __restrict__ csrc,
                                               float* __restrict__ cea,
                                               float* __restrict__ dis,
                                               float* __restrict__ invc) {
  int b = blockIdx.x;
  __shared__ int hist[128], excl[128], cur[128];
  int t = threadIdx.x;
  if (t < 128) {
    hist[t] = 0;
    cur[t] = 0;
  }
  __syncthreads();
  int cnt = bcur[b] - b * BCAP;
  if (cnt > BCAP) cnt = BCAP;
  int tb = b * BCAP;
  int ob = bbase[b];
  for (int i = t; i < cnt; i += 256) {
    uint2 r = tmp[tb + i];
    atomicAdd(&hist[(r.x >> 16) & 127], 1);
  }
  __syncthreads();
  int myDeg = (t < 128) ? hist[t] : 0;
  for (int off = 1; off < 128; off <<= 1) {
    int x = 0;
    if (t < 128 && t >= off) x = hist[t - off];
    __syncthreads();
    if (t < 128) hist[t] += x;
    __syncthreads();
  }
  if (t < 128) {
    excl[t] = hist[t] - myDeg;
    int node = (b << 7) + t;
    if (node < NN) {
      rowptr[node] = ob + excl[t];
      dis[node] = rsqrtf((float)(myDeg + 1));
      invc[node] = (myDeg > 0) ? 1.0f / (float)myDeg : 1.0f;
    }
  }
  __syncthreads();
  for (int i = t; i < cnt; i += 256) {
    uint2 r = tmp[tb + i];
    int o = (r.x >> 16) & 127;
    int p = atomicAdd(&cur[o], 1);
    int pos = ob + excl[o] + p;
    csrc[pos] = (int)(r.x & 0xffffu);
    cea[pos] = __uint_as_float(r.y);
  }
}

// ---------------- GEMM via MFMA: Y[n,FOUT] = X[n,128] @ W[128,FOUT] ----------------
// Block = 4 waves x 16 rows = 64 rows. W staged bf16 transposed in LDS
// (Wt[col][k], +8-short pad -> 2-way bank aliasing = free). X tile staged bf16.
// Per wave: 4 K-steps x (1 A-frag + NT B-frags + NT mfma_f32_16x16x32_bf16).
template <int FOUT, bool IN_BF, bool OUT_BF>
__global__ __launch_bounds__(256) void k_gemm(const void* __restrict__ Xv,
                                              const float* __restrict__ W,
                                              void* __restrict__ Yv, int n) {
  const int NT = FOUT / 16;  // 16x16 col-tiles per wave
  __shared__ __align__(16) unsigned short Wt[FOUT][136];
  __shared__ __align__(16) unsigned short Xs[64][136];
  int t = threadIdx.x;
  int row0 = blockIdx.x * 64;
  for (int idx = t; idx < 128 * FOUT; idx += 256) {
    int k = idx / FOUT, col = idx % FOUT;
    Wt[col][k] = (unsigned short)f2bf(W[idx]);
  }
  if (IN_BF) {
    const uint32* Xb = (const uint32*)Xv;
    for (int idx = t; idx < 64 * 64; idx += 256) {
      int r = idx >> 6, c = idx & 63;
      uint32 v = (row0 + r < n) ? Xb[(size_t)(row0 + r) * 64 + c] : 0u;
      *(uint32*)&Xs[r][c * 2] = v;
    }
  } else {
    const float* Xf = (const float*)Xv;
    for (int idx = t; idx < 64 * 64; idx += 256) {
      int r = idx >> 6, c = idx & 63;
      float2 v = make_float2(0.f, 0.f);
      if (row0 + r < n) v = ((const float2*)(Xf + (size_t)(row0 + r) * 128))[c];
      *(uint32*)&Xs[r][c * 2] = pack2(v.x, v.y);
    }
  }
  __syncthreads();
  int lane = t & 63, wv = t >> 6;
  int mrow = lane & 15, q = lane >> 4;
  f32x4 acc[NT];
#pragma unroll
  for (int c = 0; c < NT; c++) acc[c] = (f32x4){0.f, 0.f, 0.f, 0.f};
#pragma unroll
  for (int kt = 0; kt < 4; kt++) {
    bf16x8 af = *(const bf16x8*)&Xs[wv * 16 + mrow][kt * 32 + q * 8];
#pragma unroll
    for (int c = 0; c < NT; c++) {
      bf16x8 bfg = *(const bf16x8*)&Wt[c * 16 + mrow][kt * 32 + q * 8];
      acc[c] = __builtin_amdgcn_mfma_f32_16x16x32_bf16(af, bfg, acc[c], 0, 0, 0);
    }
  }
  // D: col = lane&15, row = (lane>>4)*4 + reg   [verified m89/m91]
#pragma unroll
  for (int c = 0; c < NT; c++) {
    int cg = c * 16 + mrow;
#pragma unroll
    for (int r = 0; r < 4; r++) {
      int rg = row0 + wv * 16 + q * 4 + r;
      if (rg < n) {
        if (OUT_BF)
          ((unsigned short*)Yv)[(size_t)rg * FOUT + cg] = (unsigned short)f2bf(acc[c][r]);
        else
          ((float*)Yv)[(size_t)rg * FOUT + cg] = acc[c][r];
      }
    }
  }
}

// ------- GCN aggregation, bf16 tables (F=128): H = agg + dis^2*XW + b -------
__global__ __launch_bounds__(256) void k_agg_bf(const uint32* __restrict__ XWb,
                                                const float* __restrict__ dis,
                                                const int* __restrict__ rowptr,
                                                const int* __restrict__ csrc,
                                                const float* __restrict__ bias,
                                                uint32* __restrict__ Hb, int n) {
  int lane = threadIdx.x & 63;
  int node = blockIdx.x * 4 + (threadIdx.x >> 6);
  if (node >= n) return;
  float dn = dis[node];
  int beg = rowptr[node], end = rowptr[node + 1];
  float ax = 0.f, ay = 0.f;
  int i = beg;
  for (; i + 4 <= end; i += 4) {
    int s0 = csrc[i], s1 = csrc[i + 1], s2 = csrc[i + 2], s3 = csrc[i + 3];
    float n0 = dn * dis[s0], n1 = dn * dis[s1], n2 = dn * dis[s2], n3 = dn * dis[s3];
    uint32 p0 = XWb[(size_t)s0 * 64 + lane];
    uint32 p1 = XWb[(size_t)s1 * 64 + lane];
    uint32 p2 = XWb[(size_t)s2 * 64 + lane];
    uint32 p3 = XWb[(size_t)s3 * 64 + lane];
    ax += n0 * bflo(p0) + n1 * bflo(p1) + n2 * bflo(p2) + n3 * bflo(p3);
    ay += n0 * bfhi(p0) + n1 * bfhi(p1) + n2 * bfhi(p2) + n3 * bfhi(p3);
  }
  for (; i < end; i++) {
    int s = csrc[i];
    float nr = dn * dis[s];
    uint32 p = XWb[(size_t)s * 64 + lane];
    ax += nr * bflo(p);
    ay += nr * bfhi(p);
  }
  uint32 ps = XWb[(size_t)node * 64 + lane];
  float2 bb = ((const float2*)bias)[lane];
  float d2 = dn * dn;
  float hx = ax + d2 * bflo(ps) + bb.x;
  float hy = ay + d2 * bfhi(ps) + bb.y;
  Hb[(size_t)node * 64 + lane] = pack2(hx, hy);
}

// -- mean-agg of h[src]+relu(ea*ew+eb), ReLU+LN epilogue, bf16 tables (F=128) --
__global__ __launch_bounds__(256) void k_msg_bf(const uint32* __restrict__ Hb,
                                                const float* __restrict__ ew,
                                                const float* __restrict__ eb,
                                                const int* __restrict__ rowptr,
                                                const int* __restrict__ csrc,
                                                const float* __restrict__ cea,
                                                const float* __restrict__ invc,
                                                const float* __restrict__ lng,
                                                const float* __restrict__ lnb,
                                                uint32* __restrict__ OUTb, int n) {
  int lane = threadIdx.x & 63;
  int node = blockIdx.x * 4 + (threadIdx.x >> 6);
  if (node >= n) return;
  int beg = rowptr[node], end = rowptr[node + 1];
  float2 w = ((const float2*)ew)[lane];
  float2 b = ((const float2*)eb)[lane];
  float ax = 0.f, ay = 0.f;
  int i = beg;
  for (; i + 4 <= end; i += 4) {
    int s0 = csrc[i], s1 = csrc[i + 1], s2 = csrc[i + 2], s3 = csrc[i + 3];
    float a0 = cea[i], a1 = cea[i + 1], a2 = cea[i + 2], a3 = cea[i + 3];
    uint32 p0 = Hb[(size_t)s0 * 64 + lane];
    uint32 p1 = Hb[(size_t)s1 * 64 + lane];
    uint32 p2 = Hb[(size_t)s2 * 64 + lane];
    uint32 p3 = Hb[(size_t)s3 * 64 + lane];
    ax += bflo(p0) + fmaxf(a0 * w.x + b.x, 0.f) + bflo(p1) + fmaxf(a1 * w.x + b.x, 0.f) +
          bflo(p2) + fmaxf(a2 * w.x + b.x, 0.f) + bflo(p3) + fmaxf(a3 * w.x + b.x, 0.f);
    ay += bfhi(p0) + fmaxf(a0 * w.y + b.y, 0.f) + bfhi(p1) + fmaxf(a1 * w.y + b.y, 0.f) +
          bfhi(p2) + fmaxf(a2 * w.y + b.y, 0.f) + bfhi(p3) + fmaxf(a3 * w.y + b.y, 0.f);
  }
  for (; i < end; i++) {
    int s = csrc[i];
    float a = cea[i];
    uint32 p = Hb[(size_t)s * 64 + lane];
    ax += bflo(p) + fmaxf(a * w.x + b.x, 0.f);
    ay += bfhi(p) + fmaxf(a * w.y + b.y, 0.f);
  }
  float ic = invc[node];
  float ox = fmaxf(ax * ic, 0.f);
  float oy = fmaxf(ay * ic, 0.f);
  float s1 = ox + oy;
  float s2 = ox * ox + oy * oy;
  for (int off = 32; off; off >>= 1) {
    s1 += __shfl_xor(s1, off, 64);
    s2 += __shfl_xor(s2, off, 64);
  }
  float mu = s1 * (1.f / 128.f);
  float var = s2 * (1.f / 128.f) - mu * mu;
  float r = rsqrtf(var + LN_EPS);
  float2 g = ((const float2*)lng)[lane];
  float2 bb = ((const float2*)lnb)[lane];
  ox = (ox - mu) * r * g.x + bb.x;
  oy = (oy - mu) * r * g.y + bb.y;
  OUTb[(size_t)node * 64 + lane] = pack2(ox, oy);
}

// ---------------- fp32 layer-2 kernels (F=64, output precision) ----------------
__global__ __launch_bounds__(256) void k_agg64(const float* __restrict__ XW,
                                               const float* __restrict__ dis,
                                               const int* __restrict__ rowptr,
                                               const int* __restrict__ csrc,
                                               const float* __restrict__ bias,
                                               float* __restrict__ H, int n) {
  int lane = threadIdx.x & 63;
  int node = blockIdx.x * 4 + (threadIdx.x >> 6);
  if (node >= n) return;
  float dn = dis[node];
  int beg = rowptr[node], end = rowptr[node + 1];
  float acc = 0.f;
  int i = beg;
  for (; i + 4 <= end; i += 4) {
    int s0 = csrc[i], s1 = csrc[i + 1], s2 = csrc[i + 2], s3 = csrc[i + 3];
    float n0 = dn * dis[s0], n1 = dn * dis[s1], n2 = dn * dis[s2], n3 = dn * dis[s3];
    acc += n0 * XW[(size_t)s0 * 64 + lane] + n1 * XW[(size_t)s1 * 64 + lane] +
           n2 * XW[(size_t)s2 * 64 + lane] + n3 * XW[(size_t)s3 * 64 + lane];
  }
  for (; i < end; i++) {
    int s = csrc[i];
    acc += dn * dis[s] * XW[(size_t)s * 64 + lane];
  }
  float d2 = dn * dn;
  H[(size_t)node * 64 + lane] = acc + d2 * XW[(size_t)node * 64 + lane] + bias[lane];
}

__global__ __launch_bounds__(256) void k_msg64(const float* __restrict__ H,
                                               const float* __restrict__ ew,
                                               const float* __restrict__ eb,
                                               const int* __restrict__ rowptr,
                                               const int* __restrict__ csrc,
                                               const float* __restrict__ cea,
                                               const float* __restrict__ invc,
                                               float* __restrict__ OUT, int n) {
  int lane = threadIdx.x & 63;
  int node = blockIdx.x * 4 + (threadIdx.x >> 6);
  if (node >= n) return;
  int beg = rowptr[node], end = rowptr[node + 1];
  float w = ew[lane], b = eb[lane];
  float acc = 0.f;
  int i = beg;
  for (; i + 4 <= end; i += 4) {
    int s0 = csrc[i], s1 = csrc[i + 1], s2 = csrc[i + 2], s3 = csrc[i + 3];
    float a0 = cea[i], a1 = cea[i + 1], a2 = cea[i + 2], a3 = cea[i + 3];
    acc += H[(size_t)s0 * 64 + lane] + fmaxf(a0 * w + b, 0.f) +
           H[(size_t)s1 * 64 + lane] + fmaxf(a1 * w + b, 0.f) +
           H[(size_t)s2 * 64 + lane] + fmaxf(a2 * w + b, 0.f) +
           H[(size_t)s3 * 64 + lane] + fmaxf(a3 * w + b, 0.f);
  }
  for (; i < end; i++) {
    int s = csrc[i];
    acc += H[(size_t)s * 64 + lane] + fmaxf(cea[i] * w + b, 0.f);
  }
  OUT[(size_t)node * 64 + lane] = acc * invc[node];
}

// ------- global mean pool ----------
#define POOL_BLOCKS 256
__global__ __launch_bounds__(256) void k_pool_partial(const float* __restrict__ H,
                                                      const int* __restrict__ batch,
                                                      float* __restrict__ Z, int n) {
  int lane = threadIdx.x & 63;
  int wid = blockIdx.x * 4 + (threadIdx.x >> 6);
  const int WAVES = POOL_BLOCKS * 4;
  int per = (n + WAVES - 1) / WAVES;
  int beg = wid * per;
  int end = beg + per;
  if (end > n) end = n;
  if (beg >= end) return;
  int g = batch[beg];
  float acc = 0.f;
  for (int i = beg; i < end; i++) {
    int gi = batch[i];
    if (gi != g) {
      atomicAdd(&Z[g * 64 + lane], acc);
      acc = 0.f;
      g = gi;
    }
    acc += H[(size_t)i * 64 + lane];
  }
  atomicAdd(&Z[g * 64 + lane], acc);
}

__global__ __launch_bounds__(64) void k_pool_div(float* __restrict__ Z,
                                                 const int* __restrict__ batch, int n) {
  int g = blockIdx.x;
  __shared__ int scnt;
  if (threadIdx.x == 0) {
    int lo = 0, hi = n;
    while (lo < hi) { int m = (lo + hi) >> 1; if (batch[m] < g) lo = m + 1; else hi = m; }
    int b0 = lo;
    lo = 0; hi = n;
    while (lo < hi) { int m = (lo + hi) >> 1; if (batch[m] < g + 1) lo = m + 1; else hi = m; }
    scnt = lo - b0;
  }
  __syncthreads();
  float c = (float)scnt;
  if (c < 1.f) c = 1.f;
  Z[g * 64 + threadIdx.x] /= c;
}

extern "C" void kernel_launch(void* const* d_in, const int* in_sizes, int n_in,
                              void* d_out, int out_size, void* d_ws, size_t ws_size,
                              hipStream_t stream) {
  const float* x = (const float*)d_in[0];
  const int* ei = (const int*)d_in[1];
  const float* ea = (const float*)d_in[2];
  const int* batch = (const int*)d_in[3];
  const float* gw0 = (const float*)d_in[4];
  const float* gb0 = (const float*)d_in[5];
  const float* ew0 = (const float*)d_in[6];
  const float* eb0 = (const float*)d_in[7];
  const float* lg0 = (const float*)d_in[8];
  const float* lb0 = (const float*)d_in[9];
  const float* gw1 = (const float*)d_in[10];
  const float* gb1 = (const float*)d_in[11];
  const float* ew1 = (const float*)d_in[12];
  const float* eb1 = (const float*)d_in[13];
  const float* lg1 = (const float*)d_in[14];
  const float* lb1 = (const float*)d_in[15];
  const float* gw2 = (const float*)d_in[16];
  const float* gb2 = (const float*)d_in[17];
  const float* ew2 = (const float*)d_in[18];
  const float* eb2 = (const float*)d_in[19];
  float* out = (float*)d_out;

  const int* src = ei;
  const int* dst = ei + NE;

  char* w = (char*)d_ws;
  size_t off = 0;
  auto alloc = [&](size_t bytes) -> void* {
    void* p = (void*)(w + off);
    off = (off + bytes + 255) & ~(size_t)255;
    return p;
  };
  int* rowptr = (int*)alloc((NN + 1) * sizeof(int));
  int* bcur = (int*)alloc(NBUK * sizeof(int));
  int* bbase = (int*)alloc((NBUK + 1) * sizeof(int));
  int* csrc = (int*)alloc(NE * sizeof(int));
  float* cea = (float*)alloc(NE * sizeof(float));
  float* dis = (float*)alloc(NN * sizeof(float));
  float* invc = (float*)alloc(NN * sizeof(float));
  uint32* B1b = (uint32*)alloc((size_t)NN * 64 * sizeof(uint32));  // 128 bf16/row
  uint32* B2b = (uint32*)alloc((size_t)NN * 64 * sizeof(uint32));
  float* F1 = (float*)alloc((size_t)NN * 64 * sizeof(float));  // 12.8 MB
  float* F2 = (float*)alloc((size_t)NN * 64 * sizeof(float));
  uint2* tmp = (uint2*)F1;  // 9.6 MB needed; F1 dead until layer-2 GEMM

  // ---- CSR build (bucket counting sort) ----
  hipLaunchKernelGGL(k_init_bcur, dim3((NBUK + 255) / 256), dim3(256), 0, stream, bcur);
  hipLaunchKernelGGL(k_bucket, dim3((NE + EPB - 1) / EPB), dim3(1024), 0, stream, src, dst, ea,
                     bcur, tmp, NE);
  hipLaunchKernelGGL(k_bscan, dim3(1), dim3(512), 0, stream, bcur, bbase, rowptr);
  hipLaunchKernelGGL(k_bsort, dim3(NBUK), dim3(256), 0, stream, tmp, bcur, bbase, rowptr, csrc,
                     cea, dis, invc);

  dim3 gemm_grid((NN + 63) / 64), tb(256);
  dim3 node_grid((NN + 3) / 4);

  // Layer 0: x(fp32) -> B1b(xw bf16) -> B2b(h bf16) -> B1b(relu+LN bf16)
  hipLaunchKernelGGL((k_gemm<128, false, true>), gemm_grid, tb, 0, stream, x, gw0, B1b, NN);
  hipLaunchKernelGGL(k_agg_bf, node_grid, tb, 0, stream, B1b, dis, rowptr, csrc, gb0, B2b, NN);
  hipLaunchKernelGGL(k_msg_bf, node_grid, tb, 0, stream, B2b, ew0, eb0, rowptr, csrc, cea, invc,
                     lg0, lb0, B1b, NN);
  // Layer 1: B1b -> B2b(xw) -> B1b(h) -> B2b(relu+LN)
  hipLaunchKernelGGL((k_gemm<128, true, true>), gemm_grid, tb, 0, stream, B1b, gw1, B2b, NN);
  hipLaunchKernelGGL(k_agg_bf, node_grid, tb, 0, stream, B2b, dis, rowptr, csrc, gb1, B1b, NN);
  hipLaunchKernelGGL(k_msg_bf, node_grid, tb, 0, stream, B1b, ew1, eb1, rowptr, csrc, cea, invc,
                     lg1, lb1, B2b, NN);
  // Layer 2 (fp32 out): B2b -> F1(xw) -> F2(h) -> d_out   (tmp dead by now)
  hipLaunchKernelGGL((k_gemm<64, true, false>), gemm_grid, tb, 0, stream, B2b, gw2, F1, NN);
  hipLaunchKernelGGL(k_agg64, node_grid, tb, 0, stream, F1, dis, rowptr, csrc, gb2, F2, NN);
  hipLaunchKernelGGL(k_msg64, node_grid, tb, 0, stream, F2, ew2, eb2, rowptr, csrc, cea, invc,
                     out, NN);
  // Pool
  float* Z = out + (size_t)NN * 64;
  hipLaunchKernelGGL(k_zero_f, dim3((NG * 64 + 255) / 256), dim3(256), 0, stream, Z, NG * 64);
  hipLaunchKernelGGL(k_pool_partial, dim3(POOL_BLOCKS), tb, 0, stream, out, batch, Z, NN);
  hipLaunchKernelGGL(k_pool_div, dim3(NG), dim3(64), 0, stream, Z, batch, NN);
}